// Round 3
// baseline (335.923 us; speedup 1.0000x reference)
//
#include <hip/hip_runtime.h>
#include <cstdint>
#include <cstddef>

#define NN   50000
#define FIN  128
#define HD   128
#define EE   800000
#define C3   384   // 3*H
#define NOUT 40

#define SC_ELEMS 512
#define SC_BLKS  ((NN + SC_ELEMS - 1) / SC_ELEMS)   // 98
#define NBLK ((NN + 127) / 128)                     // 391 row-blocks

#define SPLIT_BLKS ((NN + 4) / 4)                   // 12501 (includes ZROW)

#define NBUCK ((NN + 511) / 512)                    // 98 coarse dst-buckets
#define BCAP  16384                                 // per-bucket ebuf capacity
#define BK_BLKS ((EE + 8191) / 8192)                // 98 bucketing blocks
#define SCAP  12288                                 // csr_build LDS staging

#define REC_CAP 252                                 // per-dst fast-path edge records
#define ZROW NN                                     // zeroed xb row for pad records

#define LDSW 132   // padded epilogue LDS row stride (ushorts)

typedef __attribute__((ext_vector_type(8))) short s8v;   // 8 x bf16 (4 VGPR)
typedef __attribute__((ext_vector_type(4))) float f4v;   // MFMA acc
typedef __attribute__((ext_vector_type(4))) ushort u4v;  // 4 x bf16 (8B)

typedef const __attribute__((address_space(1))) unsigned int* guintp;
typedef __attribute__((address_space(3))) unsigned int* luintp;

static __device__ __forceinline__ void async_copy16(const void* g, void* l) {
    __builtin_amdgcn_global_load_lds((guintp)g, (luintp)l, 16, 0, 0);
}

// ---------- bf16 helpers ----------
static __device__ __forceinline__ float b2f(ushort u) {
    return __uint_as_float((unsigned)u << 16);
}
static __device__ __forceinline__ ushort f2b(float v) {
    unsigned u = __float_as_uint(v);
    unsigned r = u + 0x7fffu + ((u >> 16) & 1u);
    return (ushort)(r >> 16);
}

// ---------- x -> bf16 + attention dots; node NN is the zeroed pad row ----------
__global__ __launch_bounds__(256) void k_split_x_att(
    const float* __restrict__ x,
    const float* __restrict__ w_as, const float* __restrict__ w_ad,
    ushort* __restrict__ xb,
    float* __restrict__ a_s, float* __restrict__ a_d)
{
    int node = blockIdx.x * 4 + (threadIdx.x >> 6);
    if (node > NN) return;
    int lane = threadIdx.x & 63;
    size_t o = (size_t)node * 128 + lane * 2;
    if (node == NN) {                    // ZROW: all-zero pad row
        ushort2 z; z.x = 0; z.y = 0;
        *(ushort2*)(xb + o) = z;
        return;
    }
    float2 v  = *(const float2*)(x + o);
    { ushort2 u; u.x = f2b(v.x); u.y = f2b(v.y); *(ushort2*)(xb + o) = u; }
    float2 w1 = *(const float2*)(w_as + lane * 2);
    float2 w2 = *(const float2*)(w_ad + lane * 2);
    float s1 = v.x * w1.x + v.y * w1.y;
    float s2 = v.x * w2.x + v.y * w2.y;
    #pragma unroll
    for (int off = 32; off; off >>= 1) {
        s1 += __shfl_down(s1, off);
        s2 += __shfl_down(s2, off);
    }
    if (lane == 0) { a_s[node] = s1; a_d[node] = s2; }
}

// ---------- weight transposes (single bf16 plane) + att fold ----------
__global__ void k_splitw_all(
    const float* __restrict__ Wg, const float* __restrict__ Wc,
    const float* __restrict__ Wl, const float* __restrict__ Wr,
    const float* __restrict__ W1, const float* __restrict__ W2,
    const float* __restrict__ W3,
    const float* __restrict__ asv, const float* __restrict__ adv,
    float* __restrict__ w_as, float* __restrict__ w_ad,
    ushort* __restrict__ btg, ushort* __restrict__ btc,
    ushort* __restrict__ btsg,
    ushort* __restrict__ bt1, ushort* __restrict__ bt2,
    ushort* __restrict__ bt3)
{
    int ry = blockIdx.x;
    int t = threadIdx.x;
    if (ry == 816) {
        if (t < 128) {
            float s1 = 0.f, s2 = 0.f;
            for (int j = 0; j < 128; ++j) {
                float w = Wg[t * 128 + j];
                s1 += w * asv[j];
                s2 += w * adv[j];
            }
            w_as[t] = s1; w_ad[t] = s2;
        }
        return;
    }
    const float* W = nullptr; ushort* dh; int K, Nw, n;
    bool sage = false;
    if (ry < 128)      { n = ry;       K = 128; Nw = 128; W = Wg; dh = btg; }
    else if (ry < 256) { n = ry - 128; K = 128; Nw = 128; W = Wc; dh = btc; }
    else if (ry < 384) { n = ry - 256; K = 256; Nw = 128; sage = true; dh = btsg; }
    else if (ry < 640) { n = ry - 384; K = 384; Nw = 256; W = W1; dh = bt1; }
    else if (ry < 768) { n = ry - 640; K = 256; Nw = 128; W = W2; dh = bt2; }
    else               { n = ry - 768; K = 128; Nw = 40;  W = W3; dh = bt3; }
    for (int k = t; k < K; k += 256) {
        float v;
        if (sage) v = (k < 128) ? Wl[(size_t)k * 128 + n] : Wr[(size_t)(k - 128) * 128 + n];
        else      v = (n < Nw) ? W[(size_t)k * Nw + n] : 0.f;
        dh[(size_t)n * K + k] = f2b(v);
    }
}

// ---------- MFMA GEMM: bf16 A and B, both DMA-staged via LDS ----------
// mode 0: relu(acc+bias) -> bf16 store; mode 2: acc+bias -> fp32, cols<colmax
template<int NT, int NCH, int AX>
__global__ __launch_bounds__(256, 5) void k_gemm2(
    const ushort* __restrict__ A, int K,
    const ushort* __restrict__ Bt,
    int M, int mode,
    const float* __restrict__ bias,
    float* __restrict__ Cf, int ldc,
    ushort* __restrict__ Ch, int ldch,
    int colmax)
{
    constexpr int COLS = NT * 16;
    constexpr int HOPU = 8 * COLS;       // B 16B-units per 64-k half (1 plane)
    constexpr int KTOT = NCH * 128;

    __shared__ __align__(16) ushort S[16384];   // 32 KB union
    ushort* Bs = S;
    ushort* As = S + 8192;

    const int lane = threadIdx.x & 63;
    const int wave = threadIdx.x >> 6;
    const int quad = lane >> 4;
    const int ln15 = lane & 15;
    const int brow = AX ? blockIdx.y : blockIdx.x;
    const int bcol = AX ? blockIdx.x : blockIdx.y;
    const int row0 = brow * 128 + wave * 32;
    const int col0 = bcol * COLS;
    const int Rbase = brow * 128;

    auto stageB = [&](int c, int h) {
        for (int u0 = wave * 64; u0 < HOPU; u0 += 256) {
            int u  = u0 + lane;
            int kq  = u / COLS;
            int col = u - kq * COLS;
            int kk  = c * 128 + h * 64 + kq * 8;
            const ushort* gp = Bt + (size_t)(col0 + col) * KTOT + kk;
            async_copy16(gp, (char*)Bs + (size_t)u0 * 16);
        }
    };
    auto stageA = [&](int c, int h) {
        #pragma unroll
        for (int i = 0; i < 4; ++i) {
            int u0 = (wave * 4 + i) * 64;
            int u  = u0 + lane;
            int row = u >> 3;
            int s   = u & 7;
            int sg  = s ^ (row & 7);
            int rr = Rbase + row; if (rr > M - 1) rr = M - 1;
            int kk = c * 128 + h * 64 + sg * 8;
            const ushort* gp = A + (size_t)rr * K + kk;
            async_copy16(gp, (char*)As + (size_t)u0 * 16);
        }
    };
    auto afrag = [&](int jj, int mt) -> s8v {
        int r = wave * 32 + mt * 16 + ln15;
        int sg = jj * 4 + quad;
        int unit = r * 8 + (sg ^ (r & 7));
        return *(const s8v*)(As + (size_t)unit * 8);
    };

    f4v acc[2][NT] = {};

    auto compute = [&](int jj) {
        s8v a0 = afrag(jj, 0);
        s8v a1 = afrag(jj, 1);
        #pragma unroll
        for (int t = 0; t < NT; ++t) {
            int ub = (jj * 4 + quad) * COLS + t * 16 + ln15;
            s8v b = *(const s8v*)(Bs + (size_t)ub * 8);
            acc[0][t] = __builtin_amdgcn_mfma_f32_16x16x32_bf16(a0, b, acc[0][t], 0, 0, 0);
            acc[1][t] = __builtin_amdgcn_mfma_f32_16x16x32_bf16(a1, b, acc[1][t], 0, 0, 0);
        }
    };

    stageB(0, 0); stageA(0, 0);
    __syncthreads();

    #pragma unroll
    for (int ph = 0; ph < NCH; ++ph) {
        #pragma unroll
        for (int h = 0; h < 2; ++h) {
            compute(0); compute(1);
            if (!(ph == NCH - 1 && h == 1)) {
                __syncthreads();
                int nc = ph, nh = h + 1;
                if (nh == 2) { nh = 0; ++nc; }
                stageB(nc, nh); stageA(nc, nh);
                __syncthreads();
            }
        }
    }

    if (NT == 8 && mode == 0) {
        __syncthreads();                          // staging LDS free now
        ushort* Lp = S + wave * 2176;             // wave-private quarter
        #pragma unroll
        for (int mt = 0; mt < 2; ++mt) {
            #pragma unroll
            for (int t = 0; t < NT; ++t) {
                int cc = col0 + t * 16 + ln15;
                #pragma unroll
                for (int r = 0; r < 4; ++r) {
                    float v = acc[mt][t][r] + bias[cc];
                    v = v > 0.f ? v : 0.f;
                    Lp[(quad * 4 + r) * LDSW + t * 16 + ln15] = f2b(v);
                }
            }
            int cb = (lane & 31) * 4;
            #pragma unroll
            for (int it = 0; it < 8; ++it) {
                int row2 = it * 2 + (lane >> 5);
                int rr = row0 + mt * 16 + row2;
                uint2 v = *(uint2*)(Lp + row2 * LDSW + cb);
                if (rr < M)
                    *(uint2*)(Ch + (size_t)rr * ldch + col0 + cb) = v;
            }
        }
    } else {
        #pragma unroll
        for (int t = 0; t < NT; ++t) {
            int cc = col0 + t * 16 + ln15;
            #pragma unroll
            for (int mt = 0; mt < 2; ++mt) {
                #pragma unroll
                for (int r = 0; r < 4; ++r) {
                    int rr = row0 + mt * 16 + quad * 4 + r;
                    if (rr < M && cc < colmax)
                        Cf[(size_t)rr * ldc + cc] = acc[mt][t][r] + bias[cc];
                }
            }
        }
    }
}

// ---------- merged producer GEMMs: z=0 GAT, z=1 GCN, z=2 SAGE ----------
// launch_bounds(256,3): keeps z0+z1 L2-resident hand-off (R14 lesson).
__global__ __launch_bounds__(256, 3) void k_gemm_prod(
    const ushort* __restrict__ tgb, const ushort* __restrict__ tcb,
    const ushort* __restrict__ tsb, const ushort* __restrict__ xb,
    const ushort* __restrict__ btg, const ushort* __restrict__ btc,
    const ushort* __restrict__ btsg,
    const float* __restrict__ bg, const float* __restrict__ bc,
    const float* __restrict__ bsl,
    float* __restrict__ pS, float* __restrict__ pQ,   // [NBLK][C3] partials
    ushort* __restrict__ hch)
{
    constexpr int COLS = 128;
    constexpr int HOPU = 8 * COLS;               // 1024 units per half
    __shared__ __align__(16) ushort S[16384];    // 32 KB union
    ushort* Bs = S;
    ushort* As = S + 8192;
    float* red = (float*)(S + 14336);            // 256 floats (dead As region)

    const int z = blockIdx.z;
    const ushort* A1 = (z == 0) ? tgb : (z == 1) ? tcb : tsb;
    const ushort* Bt = (z == 0) ? btg : (z == 1) ? btc : btsg;
    const float*  bias = (z == 0) ? bg : (z == 1) ? bc : bsl;
    const int nch = (z == 2) ? 2 : 1;
    const int ktot = nch * 128;

    const int lane = threadIdx.x & 63;
    const int wave = threadIdx.x >> 6;
    const int quad = lane >> 4;
    const int ln15 = lane & 15;
    const int row0 = blockIdx.x * 128 + wave * 32;
    const int Rbase = blockIdx.x * 128;

    auto stageB = [&](int c, int h) {
        for (int u0 = wave * 64; u0 < HOPU; u0 += 256) {
            int u  = u0 + lane;
            int kq  = u / COLS;
            int col = u - kq * COLS;
            int kk  = c * 128 + h * 64 + kq * 8;
            const ushort* gp = Bt + (size_t)col * ktot + kk;
            async_copy16(gp, (char*)Bs + (size_t)u0 * 16);
        }
    };
    auto stageA = [&](int c, int h) {
        #pragma unroll
        for (int i = 0; i < 4; ++i) {
            int u0 = (wave * 4 + i) * 64;
            int u  = u0 + lane;
            int row = u >> 3;
            int s   = u & 7;
            int sg  = s ^ (row & 7);
            int rr = Rbase + row; if (rr > NN - 1) rr = NN - 1;
            int kk = c * 128 + h * 64 + sg * 8;
            const ushort* gp = (kk < 128) ? (A1 + (size_t)rr * 128 + kk)
                                          : (xb + (size_t)rr * 128 + (kk - 128));
            async_copy16(gp, (char*)As + (size_t)u0 * 16);
        }
    };
    auto afrag = [&](int jj, int mt) -> s8v {
        int r = wave * 32 + mt * 16 + ln15;
        int sg = jj * 4 + quad;
        int unit = r * 8 + (sg ^ (r & 7));
        return *(const s8v*)(As + (size_t)unit * 8);
    };

    f4v acc[2][8] = {};

    auto compute = [&](int jj) {
        s8v a0 = afrag(jj, 0);
        s8v a1 = afrag(jj, 1);
        #pragma unroll
        for (int t = 0; t < 8; ++t) {
            int ub = (jj * 4 + quad) * COLS + t * 16 + ln15;
            s8v b = *(const s8v*)(Bs + (size_t)ub * 8);
            acc[0][t] = __builtin_amdgcn_mfma_f32_16x16x32_bf16(a0, b, acc[0][t], 0, 0, 0);
            acc[1][t] = __builtin_amdgcn_mfma_f32_16x16x32_bf16(a1, b, acc[1][t], 0, 0, 0);
        }
    };

    stageB(0, 0); stageA(0, 0);
    __syncthreads();

    for (int ph = 0; ph < nch; ++ph) {
        for (int h = 0; h < 2; ++h) {
            compute(0); compute(1);
            if (!(ph == nch - 1 && h == 1)) {
                __syncthreads();
                int nc = ph, nh = h + 1;
                if (nh == 2) { nh = 0; ++nc; }
                stageB(nc, nh); stageA(nc, nh);
                __syncthreads();
            }
        }
    }

    // LDS-transpose epilogue + per-lane BN partials
    __syncthreads();
    if (threadIdx.x < 256) red[threadIdx.x] = 0.f;   // As dead; red disjoint from Lp
    ushort* Lp = S + wave * 2176;
    float sp[8] = {}, qp[8] = {};
    #pragma unroll
    for (int mt = 0; mt < 2; ++mt) {
        #pragma unroll
        for (int t = 0; t < 8; ++t) {
            #pragma unroll
            for (int r = 0; r < 4; ++r) {
                int rr = row0 + mt * 16 + quad * 4 + r;
                float v = acc[mt][t][r] + bias[t * 16 + ln15];
                Lp[(quad * 4 + r) * LDSW + t * 16 + ln15] = f2b(v);
                if (rr < NN) { sp[t] += v; qp[t] += v * v; }
            }
        }
        int cb = (lane & 31) * 4;
        #pragma unroll
        for (int it = 0; it < 8; ++it) {
            int row2 = it * 2 + (lane >> 5);
            int rr = row0 + mt * 16 + row2;
            uint2 v = *(uint2*)(Lp + row2 * LDSW + cb);
            if (rr < NN)
                *(uint2*)(hch + (size_t)rr * C3 + z * 128 + cb) = v;
        }
    }
    // cross-wave LDS reduce (no contended global atomics)
    __syncthreads();
    #pragma unroll
    for (int t = 0; t < 8; ++t) {
        float s = sp[t], q = qp[t];
        s += __shfl_xor(s, 16); s += __shfl_xor(s, 32);
        q += __shfl_xor(q, 16); q += __shfl_xor(q, 32);
        if (quad == 0) {
            atomicAdd(&red[t * 16 + ln15], s);          // LDS atomic
            atomicAdd(&red[128 + t * 16 + ln15], q);
        }
    }
    __syncthreads();
    if (threadIdx.x < 128) {
        size_t o = (size_t)blockIdx.x * C3 + z * 128 + threadIdx.x;
        pS[o] = red[threadIdx.x];
        pQ[o] = red[128 + threadIdx.x];
    }
}

// ---------- hierarchical exclusive scan over (degA[i]+1) ----------
__global__ __launch_bounds__(256) void k_scan_part(
    const int* __restrict__ degA, int* __restrict__ bsum)
{
    int t = threadIdx.x;
    int b0 = blockIdx.x * SC_ELEMS;
    int i0 = b0 + t * 2;
    int v0 = (i0 < NN)     ? degA[i0] + 1     : 0;
    int v1 = (i0 + 1 < NN) ? degA[i0 + 1] + 1 : 0;
    int s = v0 + v1;
    #pragma unroll
    for (int off = 32; off; off >>= 1) s += __shfl_down(s, off);
    __shared__ int ws[4];
    if ((t & 63) == 0) ws[t >> 6] = s;
    __syncthreads();
    if (t == 0) bsum[blockIdx.x] = ws[0] + ws[1] + ws[2] + ws[3];
}

__global__ __launch_bounds__(128) void k_scan_tops(
    const int* __restrict__ bsum, int* __restrict__ boffs)
{
    __shared__ int sh[128];
    int t = threadIdx.x;
    int v = (t < SC_BLKS) ? bsum[t] : 0;
    sh[t] = v;
    __syncthreads();
    for (int off = 1; off < 128; off <<= 1) {
        int u = (t >= off) ? sh[t - off] : 0;
        __syncthreads();
        sh[t] += u;
        __syncthreads();
    }
    if (t < SC_BLKS) boffs[t] = sh[t] - v;   // exclusive
    if (t == SC_BLKS - 1) boffs[SC_BLKS] = sh[t];
}

__global__ __launch_bounds__(256) void k_scan_apply(
    const int* __restrict__ degA, const int* __restrict__ boffs,
    int* __restrict__ offs, float* __restrict__ dinv)
{
    __shared__ int sh[256];
    int t = threadIdx.x;
    int b0 = blockIdx.x * SC_ELEMS;
    int i0 = b0 + t * 2;
    int v0 = (i0 < NN)     ? degA[i0] + 1     : 0;
    int v1 = (i0 + 1 < NN) ? degA[i0 + 1] + 1 : 0;
    int pair = v0 + v1;
    sh[t] = pair;
    __syncthreads();
    for (int off = 1; off < 256; off <<= 1) {
        int u = (t >= off) ? sh[t - off] : 0;
        __syncthreads();
        sh[t] += u;
        __syncthreads();
    }
    int excl = sh[t] - pair + boffs[blockIdx.x];
    if (i0 < NN) {
        offs[i0] = excl;
        dinv[i0] = rsqrtf((float)v0);
    }
    if (i0 + 1 < NN) {
        offs[i0 + 1] = excl + v0;
        dinv[i0 + 1] = rsqrtf((float)v1);
    }
    if (blockIdx.x == SC_BLKS - 1 && t == 255) offs[NN] = excl + pair;
}

// ---------- Pass A: coarse bucket sort of edges, block-grouped writes ----------
__global__ __launch_bounds__(1024) void k_bucket(
    const int* __restrict__ e_src, const int* __restrict__ e_dst,
    int* __restrict__ bcnt, uint* __restrict__ ebuf)
{
    __shared__ uint sval[8192];          // 32 KB staged packed edges
    __shared__ int scnt[NBUCK], sbase[NBUCK];
    int t = threadIdx.x;
    if (t < NBUCK) scnt[t] = 0;
    __syncthreads();
    int e0 = blockIdx.x * 8192;
    #pragma unroll
    for (int i = 0; i < 8; ++i) {
        int g = e0 + i * 1024 + t;
        uint val = 0xffffffffu;          // sentinel (bucket 127 >= NBUCK)
        if (g < EE) {
            int d = e_dst[g];
            int s = e_src[g];
            int b = d >> 9;
            val = ((uint)b << 25) | ((uint)(d & 511) << 16) | (uint)s;
            atomicAdd(&scnt[b], 1);
        }
        sval[i * 1024 + t] = val;
    }
    __syncthreads();
    if (t < NBUCK) {
        sbase[t] = atomicAdd(&bcnt[t], scnt[t]);   // reserve contiguous run
        scnt[t] = 0;                                // reuse as local cursor
    }
    __syncthreads();
    #pragma unroll
    for (int i = 0; i < 8; ++i) {
        uint val = sval[i * 1024 + t];
        if (val != 0xffffffffu) {
            int b = val >> 25;
            int lo = atomicAdd(&scnt[b], 1);
            ebuf[(size_t)b * BCAP + sbase[b] + lo] = val;
        }
    }
}

// ---------- Pass A2: per-bucket degree histogram (LDS atomics only) ----------
__global__ __launch_bounds__(1024) void k_deg(
    const int* __restrict__ bcnt, const uint* __restrict__ ebuf,
    int* __restrict__ degA)
{
    __shared__ int hist[512];
    int b = blockIdx.x, t = threadIdx.x;
    int d0 = b * 512;
    int ndst = NN - d0; if (ndst > 512) ndst = 512;
    if (t < 512) hist[t] = 0;
    __syncthreads();
    int nb = bcnt[b];
    const uint* eb = ebuf + (size_t)b * BCAP;
    for (int i = t; i < nb; i += 1024)
        atomicAdd(&hist[(eb[i] >> 16) & 511], 1);
    __syncthreads();
    if (t < ndst) degA[d0 + t] = hist[t];
}

// ---------- Pass B: in-LDS scatter per bucket, coalesced esrc writes ----------
__global__ __launch_bounds__(1024) void k_csr_build(
    const int* __restrict__ bcnt, const uint* __restrict__ ebuf,
    const int* __restrict__ offs, ushort* __restrict__ esrc)
{
    __shared__ ushort sout[SCAP];        // 24 KB staging
    __shared__ int cur[512];
    int b = blockIdx.x, t = threadIdx.x;
    int d0 = b * 512;
    int ndst = NN - d0; if (ndst > 512) ndst = 512;
    int obase = offs[d0];
    if (t < ndst) cur[t] = offs[d0 + t] - obase;
    __syncthreads();
    int nb = bcnt[b];
    const uint* eb = ebuf + (size_t)b * BCAP;
    for (int i = t; i < nb; i += 1024) {
        uint val = eb[i];
        int slot = atomicAdd(&cur[(val >> 16) & 511], 1);
        sout[slot] = (ushort)(val & 0xffffu);
    }
    if (t < ndst) {                      // self loops
        int slot = atomicAdd(&cur[t], 1);
        sout[slot] = (ushort)(d0 + t);
    }
    __syncthreads();
    int total = offs[d0 + ndst] - obase;
    for (int i = t; i < total; i += 1024)
        esrc[obase + i] = sout[i];       // contiguous full-line writes
}

// ---------- CSR gather: LDS edge records, broadcast reads, mov-free pipeline ----
// Phase A/B/C: per-dst softmax (max -> exp/denom -> packed {pw, srow} records in
// LDS, padded with {0, ZROW}). Phase D hot loop: half-wave-uniform ds_read_b64
// broadcast (no shuffles), dual-body unroll (no rotation movs), no validity
// masks (pads hit the zeroed ZROW through the same FMA path).
__global__ __launch_bounds__(256) void k_gather(
    const ushort* __restrict__ esrc, const int* __restrict__ offs,
    const float* __restrict__ a_s, const float* __restrict__ a_d,
    const float* __restrict__ dinv,
    const ushort* __restrict__ xb,
    ushort* __restrict__ tgb, ushort* __restrict__ tcb,
    ushort* __restrict__ tsb)
{
    __shared__ uint2 recs[4][256];       // 8 KB: per-wave edge records
    int wv = threadIdx.x >> 6;
    int d = blockIdx.x * 4 + wv;
    if (d >= NN) return;
    int lane = threadIdx.x & 63;
    int sub = lane & 31;                 // column group: cols sub*4 .. sub*4+3
    int grp = lane >> 5;                 // which edge of the pass
    uint2* rec = recs[wv];
    int beg = offs[d], end = offs[d + 1];
    int cnt = end - beg;
    float ad = a_d[d], dd = dinv[d];
    int stored = cnt < REC_CAP ? cnt : REC_CAP;

    // ---- phase A: e + wc into records, track max ----
    float mloc = -3.0e38f;
    for (int b = 0; b < cnt; b += 64) {
        int j = b + lane;
        int idx = beg + j;
        if (idx < end) {
            int s = esrc[idx];
            float e = a_s[s] + ad;
            e = (e > 0.f) ? e : 0.2f * e;
            mloc = fmaxf(mloc, e);
            if (j < REC_CAP) {
                uint2 r;
                r.x = __float_as_uint(e);
                r.y = (uint)s | ((uint)f2b(dinv[s] * dd) << 16);
                rec[j] = r;
            }
        }
    }
    float m = mloc;
    #pragma unroll
    for (int off = 1; off < 64; off <<= 1) m = fmaxf(m, __shfl_xor(m, off));

    // ---- phase B: exp + denom ----
    float denl = 0.f;
    for (int j = lane; j < stored; j += 64) {
        float ex = expf(__uint_as_float(rec[j].x) - m);
        denl += ex;
        rec[j].x = __float_as_uint(ex);
    }
    for (int idx = beg + REC_CAP + lane; idx < end; idx += 64) {   // overflow (rare)
        int s = esrc[idx];
        float e = a_s[s] + ad;
        e = (e > 0.f) ? e : 0.2f * e;
        denl += expf(e - m);
    }
    float den = denl;
    #pragma unroll
    for (int off = 1; off < 64; off <<= 1) den += __shfl_xor(den, off);
    float rden = 1.f / den;

    // ---- phase C: finalize packed records {pw, srow}; pad with {0, ZROW} ----
    for (int j = lane; j < stored; j += 64) {
        uint2 r = rec[j];
        float wg = __uint_as_float(r.x) * rden;
        uint2 q;
        q.x = (uint)f2b(wg) | (r.y & 0xffff0000u);
        q.y = r.y & 0xffffu;
        rec[j] = q;
    }
    int Pcnt = (stored + 3) & ~3;
    if (lane < Pcnt + 4 - stored) {
        uint2 q; q.x = 0u; q.y = (uint)ZROW;
        rec[stored + lane] = q;
    }

    // ---- phase D: hot accumulate (2 edges/pass, 4 edges/body) ----
    float tg[4] = {}, tc[4] = {}, ts[4] = {};
    const ushort* xbs = xb + sub * 4;
    auto ldx = [&](uint srow) -> u4v {
        return *(const u4v*)(xbs + (size_t)srow * 128);
    };
    auto fmacc = [&](u4v x4, uint pw) {
        float wg = __uint_as_float(pw << 16);          // bf16 low  -> f32
        float wc = __uint_as_float(pw & 0xffff0000u);  // bf16 high -> f32
        #pragma unroll
        for (int k = 0; k < 4; ++k) {
            float xv = b2f(x4[k]);
            tg[k] += wg * xv;
            tc[k] += wc * xv;
            ts[k] += xv;                               // pads: x = 0 (ZROW)
        }
    };

    int mB = Pcnt >> 2;                  // bodies (4 edges each), >= 1
    uint2 rA0 = rec[grp],     rA1 = rec[2 + grp];
    u4v   xA0 = ldx(rA0.y),   xA1 = ldx(rA1.y);
    uint2 rB0, rB1; u4v xB0, xB1;
    int i = 0;
    for (;;) {
        rB0 = rec[4 * i + 4 + grp]; xB0 = ldx(rB0.y);   // prefetch (pads: safe)
        rB1 = rec[4 * i + 6 + grp]; xB1 = ldx(rB1.y);
        fmacc(xA0, rA0.x); fmacc(xA1, rA1.x);
        if (++i >= mB) break;
        rA0 = rec[4 * i + 4 + grp]; xA0 = ldx(rA0.y);
        rA1 = rec[4 * i + 6 + grp]; xA1 = ldx(rA1.y);
        fmacc(xB0, rB0.x); fmacc(xB1, rB1.x);
        if (++i >= mB) break;
    }

    // ---- overflow accumulate (never taken for this input) ----
    for (int base = beg + REC_CAP; base < end; base += 64) {
        int idx = base + lane;
        int s = ZROW; uint pw = 0;
        if (idx < end) {
            int ss = esrc[idx];
            float e = a_s[ss] + ad;
            e = (e > 0.f) ? e : 0.2f * e;
            pw = (uint)f2b(expf(e - m) * rden) | ((uint)f2b(dinv[ss] * dd) << 16);
            s = ss;
        }
        int cb = end - base; if (cb > 64) cb = 64;
        for (int j = 0; j < cb; j += 2) {
            int jj = j + grp;
            int sa = __shfl(s, jj);
            uint pa = (uint)__shfl((int)pw, jj);
            bool vv = jj < cb;
            sa = vv ? sa : ZROW;
            pa = vv ? pa : 0u;
            fmacc(ldx((uint)sa), pa);
        }
    }

    // ---- cross-half reduce; lanes 0..31 finalize 4 cols each ----
    #pragma unroll
    for (int k = 0; k < 4; ++k) {
        tg[k] += __shfl_xor(tg[k], 32);
        tc[k] += __shfl_xor(tc[k], 32);
        ts[k] += __shfl_xor(ts[k], 32);
    }
    if (lane < 32) {
        u4v xd = *(const u4v*)(xb + (size_t)d * 128 + lane * 4);
        int cs = cnt - 1;
        float rc = 1.f / (float)(cs > 1 ? cs : 1);
        u4v og, oc, os;
        #pragma unroll
        for (int k = 0; k < 4; ++k) {
            og[k] = f2b(tg[k]);
            oc[k] = f2b(tc[k]);
            os[k] = f2b((ts[k] - b2f(xd[k])) * rc);
        }
        size_t row = (size_t)d * 128 + lane * 4;
        *(u4v*)(tgb + row) = og;
        *(u4v*)(tcb + row) = oc;
        *(u4v*)(tsb + row) = os;
    }
}

// ---------- BN final: reduce per-block partials, fold gamma/beta ----------
__global__ void k_bn_final(const float* __restrict__ pS, const float* __restrict__ pQ,
                           const float* __restrict__ gamma, const float* __restrict__ beta,
                           float* __restrict__ scale, float* __restrict__ shift)
{
    int j = blockIdx.x * 64 + threadIdx.x;
    if (j >= C3) return;
    float s = 0.f, q = 0.f;
    for (int r = 0; r < NBLK; ++r) {
        s += pS[(size_t)r * C3 + j];
        q += pQ[(size_t)r * C3 + j];
    }
    const float rn = 1.f / (float)NN;
    float mu  = s * rn;
    float var = q * rn - mu * mu;
    float sc  = gamma[j] * rsqrtf(var + 1e-5f);
    scale[j] = sc;
    shift[j] = beta[j] - mu * sc;
}

// ---------- in-place BN+relu of hcat (8 elems/thread, 16B ld/st) ----------
__global__ __launch_bounds__(256) void k_bnrelu(
    ushort* __restrict__ hch,
    const float* __restrict__ scale, const float* __restrict__ shift)
{
    int p = blockIdx.x * blockDim.x + threadIdx.x;
    if (p >= NN * 48) return;
    int cidx = (p % 48) * 8;
    size_t o = (size_t)p * 8;
    uint4 w = *(uint4*)(hch + o);
    uint wr[4] = {w.x, w.y, w.z, w.w};
    uint out[4];
    #pragma unroll
    for (int i = 0; i < 4; ++i) {
        ushort u0 = (ushort)(wr[i] & 0xffffu), u1 = (ushort)(wr[i] >> 16);
        int cc = cidx + i * 2;
        float v0 = b2f(u0) * scale[cc]     + shift[cc];
        float v1 = b2f(u1) * scale[cc + 1] + shift[cc + 1];
        v0 = v0 > 0.f ? v0 : 0.f;
        v1 = v1 > 0.f ? v1 : 0.f;
        out[i] = (uint)f2b(v0) | ((uint)f2b(v1) << 16);
    }
    uint4 r; r.x = out[0]; r.y = out[1]; r.z = out[2]; r.w = out[3];
    *(uint4*)(hch + o) = r;
}

extern "C" void kernel_launch(void* const* d_in, const int* in_sizes, int n_in,
                              void* d_out, int out_size, void* d_ws, size_t ws_size,
                              hipStream_t stream) {
    const float* x        = (const float*)d_in[0];
    const int*   ei       = (const int*)d_in[1];
    const float* W_gat    = (const float*)d_in[2];
    const float* att_src  = (const float*)d_in[3];
    const float* att_dst  = (const float*)d_in[4];
    const float* b_gat    = (const float*)d_in[5];
    const float* W_gcn    = (const float*)d_in[6];
    const float* b_gcn    = (const float*)d_in[7];
    const float* W_sage_l = (const float*)d_in[8];
    const float* b_sage_l = (const float*)d_in[9];
    const float* W_sage_r = (const float*)d_in[10];
    const float* W1       = (const float*)d_in[11];
    const float* b1       = (const float*)d_in[12];
    const float* W2       = (const float*)d_in[13];
    const float* b2       = (const float*)d_in[14];
    const float* W3       = (const float*)d_in[15];
    const float* b3       = (const float*)d_in[16];
    const float* gamma    = (const float*)d_in[17];
    const float* beta     = (const float*)d_in[18];

    const int* e_src = ei;
    const int* e_dst = ei + EE;

    // ---- workspace layout (16B-aligned) ----
    char* base = (char*)d_ws;
    size_t o = 0;
    ushort* hch  = (ushort*)(base + o); o += (size_t)NN * C3 * 2;
    ushort* tgb  = (ushort*)(base + o); o += (size_t)NN * 128 * 2;    // a1 overlay
    ushort* tcb  = (ushort*)(base + o); o += (size_t)NN * 128 * 2;
    ushort* tsb  = (ushort*)(base + o); o += (size_t)NN * 128 * 2;    // a2 overlay
    ushort* xb   = (ushort*)(base + o); o += (size_t)(NN + 1) * 128 * 2;  // +ZROW
    ushort* esrc = (ushort*)(base + o); o += ((size_t)(EE + NN) * 2 + 15) & ~15ull;
    int*    offs = (int*)(base + o);    o += (size_t)(NN + 16) * 4;
    float*  as_  = (float*)(base + o);  o += (size_t)NN * 4;
    float*  ad_  = (float*)(base + o);  o += (size_t)NN * 4;
    float*  dinv = (float*)(base + o);  o += (size_t)NN * 4;
    int*    bsum = (int*)(base + o);    o += 256 * 4;
    int*    boffs= (int*)(base + o);    o += 256 * 4;
    int*    degA = (int*)(base + o);    o += (size_t)NN * 4;          // fully written by k_deg
    // --- zero-init region: bcnt only ---
    int*    bcnt = (int*)(base + o);    o += 128 * 4;
    // --- end zero region ---
    float*  pS   = (float*)(base + o);  o += (size_t)NBLK * C3 * 4;   // written fully
    float*  pQ   = (float*)(base + o);  o += (size_t)NBLK * C3 * 4;
    float*  scale= (float*)(base + o);  o += C3 * 4;
    float*  shift= (float*)(base + o);  o += C3 * 4;
    float*  w_as = (float*)(base + o);  o += 128 * 4;
    float*  w_ad = (float*)(base + o);  o += 128 * 4;
    ushort* btg  = (ushort*)(base + o); o += 128 * 128 * 2;
    ushort* btc  = (ushort*)(base + o); o += 128 * 128 * 2;
    ushort* btsg = (ushort*)(base + o); o += 128 * 256 * 2;
    ushort* bt1  = (ushort*)(base + o); o += 256 * 384 * 2;
    ushort* bt2  = (ushort*)(base + o); o += 128 * 256 * 2;
    ushort* bt3  = (ushort*)(base + o); o += 48 * 128 * 2;
    // overlays (temporally disjoint)
    ushort* a1 = tgb;                        // NN*256 ushorts (tgb+tcb)
    ushort* a2 = tsb;                        // NN*128
    uint*   ebuf = (uint*)hch;               // 98*16384*4B = 6.4MB << 38.4MB; hch first
                                             // written by k_gemm_prod, after k_csr_build

    hipMemsetAsync(bcnt, 0, 128 * 4, stream);

    // ---- weight prep ----
    k_splitw_all<<<817, 256, 0, stream>>>(W_gat, W_gcn, W_sage_l, W_sage_r, W1, W2, W3,
        att_src, att_dst, w_as, w_ad, btg, btc, btsg, bt1, bt2, bt3);
    // split x + attention dots (+ ZROW zero row)
    k_split_x_att<<<SPLIT_BLKS, 256, 0, stream>>>(x, w_as, w_ad, xb, as_, ad_);

    // ---- CSR build: bucket sort -> degree -> scan -> in-LDS scatter ----
    k_bucket<<<BK_BLKS, 1024, 0, stream>>>(e_src, e_dst, bcnt, ebuf);
    k_deg<<<NBUCK, 1024, 0, stream>>>(bcnt, ebuf, degA);
    k_scan_part<<<SC_BLKS, 256, 0, stream>>>(degA, bsum);
    k_scan_tops<<<1, 128, 0, stream>>>(bsum, boffs);
    k_scan_apply<<<SC_BLKS, 256, 0, stream>>>(degA, boffs, offs, dinv);
    k_csr_build<<<NBUCK, 1024, 0, stream>>>(bcnt, ebuf, offs, esrc);

    // ---- gather (LDS edge records, broadcast reads, mov-free pipeline) ----
    k_gather<<<(NN + 3) / 4, 256, 0, stream>>>(
        esrc, offs, as_, ad_, dinv, xb, tgb, tcb, tsb);

    // ---- producers: one launch, privatized BN partials ----
    k_gemm_prod<<<dim3(NBLK, 1, 3), 256, 0, stream>>>(
        tgb, tcb, tsb, xb, btg, btc, btsg,
        b_gat, b_gcn, b_sage_l, pS, pQ, hch);

    // ---- BN fold (partials reduce) + standalone BN+relu pass ----
    k_bn_final<<<6, 64, 0, stream>>>(pS, pQ, gamma, beta, scale, shift);
    k_bnrelu<<<(NN * 48 + 255) / 256, 256, 0, stream>>>(hch, scale, shift);

    // ---- MLP ----
    k_gemm2<8, 3, 1><<<dim3(2, NBLK), 256, 0, stream>>>(
        hch, 384, bt1, NN, 0, b1, nullptr, 0, a1, 256, 256);
    k_gemm2<8, 2, 0><<<dim3(NBLK, 1), 256, 0, stream>>>(
        a1, 256, bt2, NN, 0, b2, nullptr, 0, a2, 128, 128);
    k_gemm2<3, 1, 0><<<dim3(NBLK, 1), 256, 0, stream>>>(
        a2, 128, bt3, NN, 2, b3, (float*)d_out, NOUT, nullptr, 0, NOUT);
}

// Round 4
// 326.454 us; speedup vs baseline: 1.0290x; 1.0290x over previous
//
#include <hip/hip_runtime.h>
#include <cstdint>
#include <cstddef>

#define NN   50000
#define FIN  128
#define HD   128
#define EE   800000
#define C3   384   // 3*H
#define NOUT 40

#define NBLK ((NN + 127) / 128)                     // 391 row-blocks

#define SPLIT_BLKS ((NN + 4) / 4)                   // 12501 (includes ZROW)

#define NBUCK ((NN + 511) / 512)                    // 98 coarse dst-buckets
#define BCAP  16384                                 // per-bucket ebuf capacity
#define BK_BLKS ((EE + 8191) / 8192)                // 98 bucketing blocks
#define SCAP  12288                                 // csr_build LDS staging

#define RCAP      132                               // per-dst record slots (LDS)
#define STORE_CAP 128                               // fast-path record cap
#define ZROW NN                                     // zeroed xb row for pad records

#define LDSW 132   // padded epilogue LDS row stride (ushorts)

typedef __attribute__((ext_vector_type(8))) short s8v;   // 8 x bf16 (4 VGPR)
typedef __attribute__((ext_vector_type(4))) float f4v;   // MFMA acc
typedef __attribute__((ext_vector_type(8))) ushort u8v;  // 8 x bf16 (16B)

typedef const __attribute__((address_space(1))) unsigned int* guintp;
typedef __attribute__((address_space(3))) unsigned int* luintp;

static __device__ __forceinline__ void async_copy16(const void* g, void* l) {
    __builtin_amdgcn_global_load_lds((guintp)g, (luintp)l, 16, 0, 0);
}

// ---------- bf16 helpers ----------
static __device__ __forceinline__ float b2f(ushort u) {
    return __uint_as_float((unsigned)u << 16);
}
static __device__ __forceinline__ ushort f2b(float v) {
    unsigned u = __float_as_uint(v);
    unsigned r = u + 0x7fffu + ((u >> 16) & 1u);
    return (ushort)(r >> 16);
}

// ---------- x -> bf16 + attention dots; node NN is the zeroed pad row ----------
__global__ __launch_bounds__(256) void k_split_x_att(
    const float* __restrict__ x,
    const float* __restrict__ w_as, const float* __restrict__ w_ad,
    ushort* __restrict__ xb,
    float* __restrict__ a_s, float* __restrict__ a_d)
{
    int node = blockIdx.x * 4 + (threadIdx.x >> 6);
    if (node > NN) return;
    int lane = threadIdx.x & 63;
    size_t o = (size_t)node * 128 + lane * 2;
    if (node == NN) {                    // ZROW: all-zero pad row
        ushort2 z; z.x = 0; z.y = 0;
        *(ushort2*)(xb + o) = z;
        return;
    }
    float2 v  = *(const float2*)(x + o);
    { ushort2 u; u.x = f2b(v.x); u.y = f2b(v.y); *(ushort2*)(xb + o) = u; }
    float2 w1 = *(const float2*)(w_as + lane * 2);
    float2 w2 = *(const float2*)(w_ad + lane * 2);
    float s1 = v.x * w1.x + v.y * w1.y;
    float s2 = v.x * w2.x + v.y * w2.y;
    #pragma unroll
    for (int off = 32; off; off >>= 1) {
        s1 += __shfl_down(s1, off);
        s2 += __shfl_down(s2, off);
    }
    if (lane == 0) { a_s[node] = s1; a_d[node] = s2; }
}

// ---------- weight transposes (single bf16 plane) + att fold ----------
__global__ void k_splitw_all(
    const float* __restrict__ Wg, const float* __restrict__ Wc,
    const float* __restrict__ Wl, const float* __restrict__ Wr,
    const float* __restrict__ W1, const float* __restrict__ W2,
    const float* __restrict__ W3,
    const float* __restrict__ asv, const float* __restrict__ adv,
    float* __restrict__ w_as, float* __restrict__ w_ad,
    ushort* __restrict__ btg, ushort* __restrict__ btc,
    ushort* __restrict__ btsg,
    ushort* __restrict__ bt1, ushort* __restrict__ bt2,
    ushort* __restrict__ bt3)
{
    int ry = blockIdx.x;
    int t = threadIdx.x;
    if (ry == 816) {
        if (t < 128) {
            float s1 = 0.f, s2 = 0.f;
            for (int j = 0; j < 128; ++j) {
                float w = Wg[t * 128 + j];
                s1 += w * asv[j];
                s2 += w * adv[j];
            }
            w_as[t] = s1; w_ad[t] = s2;
        }
        return;
    }
    const float* W = nullptr; ushort* dh; int K, Nw, n;
    bool sage = false;
    if (ry < 128)      { n = ry;       K = 128; Nw = 128; W = Wg; dh = btg; }
    else if (ry < 256) { n = ry - 128; K = 128; Nw = 128; W = Wc; dh = btc; }
    else if (ry < 384) { n = ry - 256; K = 256; Nw = 128; sage = true; dh = btsg; }
    else if (ry < 640) { n = ry - 384; K = 384; Nw = 256; W = W1; dh = bt1; }
    else if (ry < 768) { n = ry - 640; K = 256; Nw = 128; W = W2; dh = bt2; }
    else               { n = ry - 768; K = 128; Nw = 40;  W = W3; dh = bt3; }
    for (int k = t; k < K; k += 256) {
        float v;
        if (sage) v = (k < 128) ? Wl[(size_t)k * 128 + n] : Wr[(size_t)(k - 128) * 128 + n];
        else      v = (n < Nw) ? W[(size_t)k * Nw + n] : 0.f;
        dh[(size_t)n * K + k] = f2b(v);
    }
}

// ---------- MFMA GEMM: bf16 A and B, both DMA-staged via LDS ----------
// mode 0: relu(acc+bias) -> bf16 store; mode 2: acc+bias -> fp32, cols<colmax
template<int NT, int NCH, int AX>
__global__ __launch_bounds__(256, 5) void k_gemm2(
    const ushort* __restrict__ A, int K,
    const ushort* __restrict__ Bt,
    int M, int mode,
    const float* __restrict__ bias,
    float* __restrict__ Cf, int ldc,
    ushort* __restrict__ Ch, int ldch,
    int colmax)
{
    constexpr int COLS = NT * 16;
    constexpr int HOPU = 8 * COLS;       // B 16B-units per 64-k half (1 plane)
    constexpr int KTOT = NCH * 128;

    __shared__ __align__(16) ushort S[16384];   // 32 KB union
    ushort* Bs = S;
    ushort* As = S + 8192;

    const int lane = threadIdx.x & 63;
    const int wave = threadIdx.x >> 6;
    const int quad = lane >> 4;
    const int ln15 = lane & 15;
    const int brow = AX ? blockIdx.y : blockIdx.x;
    const int bcol = AX ? blockIdx.x : blockIdx.y;
    const int row0 = brow * 128 + wave * 32;
    const int col0 = bcol * COLS;
    const int Rbase = brow * 128;

    auto stageB = [&](int c, int h) {
        for (int u0 = wave * 64; u0 < HOPU; u0 += 256) {
            int u  = u0 + lane;
            int kq  = u / COLS;
            int col = u - kq * COLS;
            int kk  = c * 128 + h * 64 + kq * 8;
            const ushort* gp = Bt + (size_t)(col0 + col) * KTOT + kk;
            async_copy16(gp, (char*)Bs + (size_t)u0 * 16);
        }
    };
    auto stageA = [&](int c, int h) {
        #pragma unroll
        for (int i = 0; i < 4; ++i) {
            int u0 = (wave * 4 + i) * 64;
            int u  = u0 + lane;
            int row = u >> 3;
            int s   = u & 7;
            int sg  = s ^ (row & 7);
            int rr = Rbase + row; if (rr > M - 1) rr = M - 1;
            int kk = c * 128 + h * 64 + sg * 8;
            const ushort* gp = A + (size_t)rr * K + kk;
            async_copy16(gp, (char*)As + (size_t)u0 * 16);
        }
    };
    auto afrag = [&](int jj, int mt) -> s8v {
        int r = wave * 32 + mt * 16 + ln15;
        int sg = jj * 4 + quad;
        int unit = r * 8 + (sg ^ (r & 7));
        return *(const s8v*)(As + (size_t)unit * 8);
    };

    f4v acc[2][NT] = {};

    auto compute = [&](int jj) {
        s8v a0 = afrag(jj, 0);
        s8v a1 = afrag(jj, 1);
        #pragma unroll
        for (int t = 0; t < NT; ++t) {
            int ub = (jj * 4 + quad) * COLS + t * 16 + ln15;
            s8v b = *(const s8v*)(Bs + (size_t)ub * 8);
            acc[0][t] = __builtin_amdgcn_mfma_f32_16x16x32_bf16(a0, b, acc[0][t], 0, 0, 0);
            acc[1][t] = __builtin_amdgcn_mfma_f32_16x16x32_bf16(a1, b, acc[1][t], 0, 0, 0);
        }
    };

    stageB(0, 0); stageA(0, 0);
    __syncthreads();

    #pragma unroll
    for (int ph = 0; ph < NCH; ++ph) {
        #pragma unroll
        for (int h = 0; h < 2; ++h) {
            compute(0); compute(1);
            if (!(ph == NCH - 1 && h == 1)) {
                __syncthreads();
                int nc = ph, nh = h + 1;
                if (nh == 2) { nh = 0; ++nc; }
                stageB(nc, nh); stageA(nc, nh);
                __syncthreads();
            }
        }
    }

    if (NT == 8 && mode == 0) {
        __syncthreads();                          // staging LDS free now
        ushort* Lp = S + wave * 2176;             // wave-private quarter
        #pragma unroll
        for (int mt = 0; mt < 2; ++mt) {
            #pragma unroll
            for (int t = 0; t < NT; ++t) {
                int cc = col0 + t * 16 + ln15;
                #pragma unroll
                for (int r = 0; r < 4; ++r) {
                    float v = acc[mt][t][r] + bias[cc];
                    v = v > 0.f ? v : 0.f;
                    Lp[(quad * 4 + r) * LDSW + t * 16 + ln15] = f2b(v);
                }
            }
            int cb = (lane & 31) * 4;
            #pragma unroll
            for (int it = 0; it < 8; ++it) {
                int row2 = it * 2 + (lane >> 5);
                int rr = row0 + mt * 16 + row2;
                uint2 v = *(uint2*)(Lp + row2 * LDSW + cb);
                if (rr < M)
                    *(uint2*)(Ch + (size_t)rr * ldch + col0 + cb) = v;
            }
        }
    } else {
        #pragma unroll
        for (int t = 0; t < NT; ++t) {
            int cc = col0 + t * 16 + ln15;
            #pragma unroll
            for (int mt = 0; mt < 2; ++mt) {
                #pragma unroll
                for (int r = 0; r < 4; ++r) {
                    int rr = row0 + mt * 16 + quad * 4 + r;
                    if (rr < M && cc < colmax)
                        Cf[(size_t)rr * ldc + cc] = acc[mt][t][r] + bias[cc];
                }
            }
        }
    }
}

// ---------- merged producer GEMMs: z=0 GAT, z=1 GCN, z=2 SAGE ----------
// launch_bounds(256,3): keeps z0+z1 L2-resident hand-off (R14 lesson).
__global__ __launch_bounds__(256, 3) void k_gemm_prod(
    const ushort* __restrict__ tgb, const ushort* __restrict__ tcb,
    const ushort* __restrict__ tsb, const ushort* __restrict__ xb,
    const ushort* __restrict__ btg, const ushort* __restrict__ btc,
    const ushort* __restrict__ btsg,
    const float* __restrict__ bg, const float* __restrict__ bc,
    const float* __restrict__ bsl,
    float* __restrict__ pS, float* __restrict__ pQ,   // [NBLK][C3] partials
    ushort* __restrict__ hch)
{
    constexpr int COLS = 128;
    constexpr int HOPU = 8 * COLS;               // 1024 units per half
    __shared__ __align__(16) ushort S[16384];    // 32 KB union
    ushort* Bs = S;
    ushort* As = S + 8192;
    float* red = (float*)(S + 14336);            // 256 floats (dead As region)

    const int z = blockIdx.z;
    const ushort* A1 = (z == 0) ? tgb : (z == 1) ? tcb : tsb;
    const ushort* Bt = (z == 0) ? btg : (z == 1) ? btc : btsg;
    const float*  bias = (z == 0) ? bg : (z == 1) ? bc : bsl;
    const int nch = (z == 2) ? 2 : 1;
    const int ktot = nch * 128;

    const int lane = threadIdx.x & 63;
    const int wave = threadIdx.x >> 6;
    const int quad = lane >> 4;
    const int ln15 = lane & 15;
    const int row0 = blockIdx.x * 128 + wave * 32;
    const int Rbase = blockIdx.x * 128;

    auto stageB = [&](int c, int h) {
        for (int u0 = wave * 64; u0 < HOPU; u0 += 256) {
            int u  = u0 + lane;
            int kq  = u / COLS;
            int col = u - kq * COLS;
            int kk  = c * 128 + h * 64 + kq * 8;
            const ushort* gp = Bt + (size_t)col * ktot + kk;
            async_copy16(gp, (char*)Bs + (size_t)u0 * 16);
        }
    };
    auto stageA = [&](int c, int h) {
        #pragma unroll
        for (int i = 0; i < 4; ++i) {
            int u0 = (wave * 4 + i) * 64;
            int u  = u0 + lane;
            int row = u >> 3;
            int s   = u & 7;
            int sg  = s ^ (row & 7);
            int rr = Rbase + row; if (rr > NN - 1) rr = NN - 1;
            int kk = c * 128 + h * 64 + sg * 8;
            const ushort* gp = (kk < 128) ? (A1 + (size_t)rr * 128 + kk)
                                          : (xb + (size_t)rr * 128 + (kk - 128));
            async_copy16(gp, (char*)As + (size_t)u0 * 16);
        }
    };
    auto afrag = [&](int jj, int mt) -> s8v {
        int r = wave * 32 + mt * 16 + ln15;
        int sg = jj * 4 + quad;
        int unit = r * 8 + (sg ^ (r & 7));
        return *(const s8v*)(As + (size_t)unit * 8);
    };

    f4v acc[2][8] = {};

    auto compute = [&](int jj) {
        s8v a0 = afrag(jj, 0);
        s8v a1 = afrag(jj, 1);
        #pragma unroll
        for (int t = 0; t < 8; ++t) {
            int ub = (jj * 4 + quad) * COLS + t * 16 + ln15;
            s8v b = *(const s8v*)(Bs + (size_t)ub * 8);
            acc[0][t] = __builtin_amdgcn_mfma_f32_16x16x32_bf16(a0, b, acc[0][t], 0, 0, 0);
            acc[1][t] = __builtin_amdgcn_mfma_f32_16x16x32_bf16(a1, b, acc[1][t], 0, 0, 0);
        }
    };

    stageB(0, 0); stageA(0, 0);
    __syncthreads();

    for (int ph = 0; ph < nch; ++ph) {
        for (int h = 0; h < 2; ++h) {
            compute(0); compute(1);
            if (!(ph == nch - 1 && h == 1)) {
                __syncthreads();
                int nc = ph, nh = h + 1;
                if (nh == 2) { nh = 0; ++nc; }
                stageB(nc, nh); stageA(nc, nh);
                __syncthreads();
            }
        }
    }

    // LDS-transpose epilogue + per-lane BN partials
    __syncthreads();
    if (threadIdx.x < 256) red[threadIdx.x] = 0.f;   // As dead; red disjoint from Lp
    ushort* Lp = S + wave * 2176;
    float sp[8] = {}, qp[8] = {};
    #pragma unroll
    for (int mt = 0; mt < 2; ++mt) {
        #pragma unroll
        for (int t = 0; t < 8; ++t) {
            #pragma unroll
            for (int r = 0; r < 4; ++r) {
                int rr = row0 + mt * 16 + quad * 4 + r;
                float v = acc[mt][t][r] + bias[t * 16 + ln15];
                Lp[(quad * 4 + r) * LDSW + t * 16 + ln15] = f2b(v);
                if (rr < NN) { sp[t] += v; qp[t] += v * v; }
            }
        }
        int cb = (lane & 31) * 4;
        #pragma unroll
        for (int it = 0; it < 8; ++it) {
            int row2 = it * 2 + (lane >> 5);
            int rr = row0 + mt * 16 + row2;
            uint2 v = *(uint2*)(Lp + row2 * LDSW + cb);
            if (rr < NN)
                *(uint2*)(hch + (size_t)rr * C3 + z * 128 + cb) = v;
        }
    }
    // cross-wave LDS reduce (no contended global atomics)
    __syncthreads();
    #pragma unroll
    for (int t = 0; t < 8; ++t) {
        float s = sp[t], q = qp[t];
        s += __shfl_xor(s, 16); s += __shfl_xor(s, 32);
        q += __shfl_xor(q, 16); q += __shfl_xor(q, 32);
        if (quad == 0) {
            atomicAdd(&red[t * 16 + ln15], s);          // LDS atomic
            atomicAdd(&red[128 + t * 16 + ln15], q);
        }
    }
    __syncthreads();
    if (threadIdx.x < 128) {
        size_t o = (size_t)blockIdx.x * C3 + z * 128 + threadIdx.x;
        pS[o] = red[threadIdx.x];
        pQ[o] = red[128 + threadIdx.x];
    }
}

// ---------- Pass A: coarse bucket sort of edges, block-grouped writes ----------
__global__ __launch_bounds__(1024) void k_bucket(
    const int* __restrict__ e_src, const int* __restrict__ e_dst,
    int* __restrict__ bcnt, uint* __restrict__ ebuf)
{
    __shared__ uint sval[8192];          // 32 KB staged packed edges
    __shared__ int scnt[NBUCK], sbase[NBUCK];
    int t = threadIdx.x;
    if (t < NBUCK) scnt[t] = 0;
    __syncthreads();
    int e0 = blockIdx.x * 8192;
    #pragma unroll
    for (int i = 0; i < 8; ++i) {
        int g = e0 + i * 1024 + t;
        uint val = 0xffffffffu;          // sentinel (bucket 127 >= NBUCK)
        if (g < EE) {
            int d = e_dst[g];
            int s = e_src[g];
            int b = d >> 9;
            val = ((uint)b << 25) | ((uint)(d & 511) << 16) | (uint)s;
            atomicAdd(&scnt[b], 1);
        }
        sval[i * 1024 + t] = val;
    }
    __syncthreads();
    if (t < NBUCK) {
        sbase[t] = atomicAdd(&bcnt[t], scnt[t]);   // reserve contiguous run
        scnt[t] = 0;                                // reuse as local cursor
    }
    __syncthreads();
    #pragma unroll
    for (int i = 0; i < 8; ++i) {
        uint val = sval[i * 1024 + t];
        if (val != 0xffffffffu) {
            int b = val >> 25;
            int lo = atomicAdd(&scnt[b], 1);
            ebuf[(size_t)b * BCAP + sbase[b] + lo] = val;
        }
    }
}

// ---------- merged degree histogram + 2-level exclusive scan ----------
// bsum[b] = bcnt[b] + ndst(b) analytically; every block redoes the 98-bucket
// top prefix (trivial) -> kills k_scan_part/k_scan_tops/k_deg + degA buffer.
__global__ __launch_bounds__(1024) void k_degscan(
    const int* __restrict__ bcnt, const uint* __restrict__ ebuf,
    int* __restrict__ offs, float* __restrict__ dinv)
{
    __shared__ int hist[512];
    __shared__ int sh[256];
    __shared__ int btop;
    int b = blockIdx.x, t = threadIdx.x;
    int d0 = b * 512;
    if (t < 512) hist[t] = 0;
    __syncthreads();
    int nb = bcnt[b];
    const uint* eb = ebuf + (size_t)b * BCAP;
    for (int i = t; i < nb; i += 1024)
        atomicAdd(&hist[(eb[i] >> 16) & 511], 1);
    __syncthreads();
    if (t < 64) {                        // top-level exclusive prefix for bucket b
        int acc = 0;
        for (int i = t; i < b; i += 64) {
            int nd = NN - i * 512; if (nd > 512) nd = 512;
            acc += bcnt[i] + nd;
        }
        #pragma unroll
        for (int off = 32; off; off >>= 1) acc += __shfl_down(acc, off);
        if (t == 0) btop = acc;
    }
    int v0 = 0, v1 = 0;
    if (t < 256) {
        int i0g = d0 + t * 2;
        v0 = (i0g < NN) ? hist[t * 2] + 1 : 0;
        v1 = (i0g + 1 < NN) ? hist[t * 2 + 1] + 1 : 0;
        sh[t] = v0 + v1;
    }
    __syncthreads();
    for (int off = 1; off < 256; off <<= 1) {
        int u = 0;
        if (t < 256 && t >= off) u = sh[t - off];
        __syncthreads();
        if (t < 256) sh[t] += u;
        __syncthreads();
    }
    if (t < 256) {
        int pair = v0 + v1;
        int excl = sh[t] - pair + btop;
        int i0g = d0 + t * 2;
        if (i0g < NN)     { offs[i0g] = excl;          dinv[i0g] = rsqrtf((float)v0); }
        if (i0g + 1 < NN) { offs[i0g + 1] = excl + v0; dinv[i0g + 1] = rsqrtf((float)v1); }
        if (b == NBUCK - 1 && t == 255) offs[NN] = excl + pair;
    }
}

// ---------- Pass B: in-LDS scatter per bucket, coalesced esrc writes ----------
__global__ __launch_bounds__(1024) void k_csr_build(
    const int* __restrict__ bcnt, const uint* __restrict__ ebuf,
    const int* __restrict__ offs, ushort* __restrict__ esrc)
{
    __shared__ ushort sout[SCAP];        // 24 KB staging
    __shared__ int cur[512];
    int b = blockIdx.x, t = threadIdx.x;
    int d0 = b * 512;
    int ndst = NN - d0; if (ndst > 512) ndst = 512;
    int obase = offs[d0];
    if (t < ndst) cur[t] = offs[d0 + t] - obase;
    __syncthreads();
    int nb = bcnt[b];
    const uint* eb = ebuf + (size_t)b * BCAP;
    for (int i = t; i < nb; i += 1024) {
        uint val = eb[i];
        int slot = atomicAdd(&cur[(val >> 16) & 511], 1);
        sout[slot] = (ushort)(val & 0xffffu);
    }
    if (t < ndst) {                      // self loops
        int slot = atomicAdd(&cur[t], 1);
        sout[slot] = (ushort)(d0 + t);
    }
    __syncthreads();
    int total = offs[d0 + ndst] - obase;
    for (int i = t; i < total; i += 1024)
        esrc[obase + i] = sout[i];       // contiguous full-line writes
}

// ---------- CSR gather: 16-lane quads, one dst/quad, 16B row loads ----------
// Phase A/B/C at 16-lane granularity (4x lane efficiency at mean degree 17);
// phase D: one edge per quad-pass, each lane owns 8 cols (ushort8 16B load),
// uniform ds_read_b64 record broadcast, dual-body pipeline, pad records hit
// the zeroed ZROW. No cross-lane epilogue reduce needed.
__global__ __launch_bounds__(256) void k_gather(
    const ushort* __restrict__ esrc, const int* __restrict__ offs,
    const float* __restrict__ a_s, const float* __restrict__ a_d,
    const float* __restrict__ dinv,
    const ushort* __restrict__ xb,
    ushort* __restrict__ tgb, ushort* __restrict__ tcb,
    ushort* __restrict__ tsb)
{
    __shared__ uint2 recs[16][RCAP];     // 16.5 KB: per-quad edge records
    int t = threadIdx.x;
    int qid = t >> 4;
    int ln = t & 15;
    int d = blockIdx.x * 16 + qid;
    if (d >= NN) return;
    uint2* rec = recs[qid];
    int beg = offs[d], end = offs[d + 1];
    int cnt = end - beg;
    float ad = a_d[d], dd = dinv[d];
    int stored = cnt < STORE_CAP ? cnt : STORE_CAP;

    // ---- phase A: e + wc into records, track max ----
    float mloc = -3.0e38f;
    for (int b = 0; b < cnt; b += 16) {
        int j = b + ln;
        if (j < cnt) {
            int s = esrc[beg + j];
            float e = a_s[s] + ad;
            e = (e > 0.f) ? e : 0.2f * e;
            mloc = fmaxf(mloc, e);
            if (j < STORE_CAP) {
                uint2 r;
                r.x = __float_as_uint(e);
                r.y = (uint)s | ((uint)f2b(dinv[s] * dd) << 16);
                rec[j] = r;
            }
        }
    }
    float m = mloc;
    #pragma unroll
    for (int off = 1; off < 16; off <<= 1) m = fmaxf(m, __shfl_xor(m, off, 16));

    // ---- phase B: exp + denom ----
    float denl = 0.f;
    for (int j = ln; j < stored; j += 16) {
        float ex = expf(__uint_as_float(rec[j].x) - m);
        denl += ex;
        rec[j].x = __float_as_uint(ex);
    }
    for (int idx = beg + STORE_CAP + ln; idx < end; idx += 16) {   // overflow (rare)
        int s = esrc[idx];
        float e = a_s[s] + ad;
        e = (e > 0.f) ? e : 0.2f * e;
        denl += expf(e - m);
    }
    float den = denl;
    #pragma unroll
    for (int off = 1; off < 16; off <<= 1) den += __shfl_xor(den, off, 16);
    float rden = 1.f / den;

    // ---- phase C: finalize packed records {pw, srow}; 2 pads {0, ZROW} ----
    for (int j = ln; j < stored; j += 16) {
        uint2 r = rec[j];
        uint2 q;
        q.x = (uint)f2b(__uint_as_float(r.x) * rden) | (r.y & 0xffff0000u);
        q.y = r.y & 0xffffu;
        rec[j] = q;
    }
    if (ln < 2) { uint2 q; q.x = 0u; q.y = (uint)ZROW; rec[stored + ln] = q; }

    // ---- phase D: hot accumulate (1 edge/quad-pass, dual-body pipeline) ----
    float tg[8] = {}, tc[8] = {}, ts[8] = {};
    const ushort* xbs = xb + ln * 8;
    auto ldx = [&](uint srow) -> u8v {
        return *(const u8v*)(xbs + (size_t)srow * 128);
    };
    auto fmacc = [&](u8v x8, uint pw) {
        float wg = __uint_as_float(pw << 16);          // bf16 low  -> f32
        float wc = __uint_as_float(pw & 0xffff0000u);  // bf16 high -> f32
        #pragma unroll
        for (int k = 0; k < 8; ++k) {
            float xv = b2f(x8[k]);
            tg[k] += wg * xv;
            tc[k] += wc * xv;
            ts[k] += xv;                               // pads: x = 0 (ZROW)
        }
    };

    int Pcnt = (stored + 1) & ~1;        // even, >= 2 (self-loop => cnt >= 1)
    uint2 rA = rec[0]; u8v xA = ldx(rA.y);
    uint2 rB; u8v xB;
    int j = 0;
    for (;;) {
        rB = rec[j + 1]; xB = ldx(rB.y); // prefetch (pads: safe)
        fmacc(xA, rA.x);
        if (++j >= Pcnt) break;
        rA = rec[j + 1]; xA = ldx(rA.y);
        fmacc(xB, rB.x);
        if (++j >= Pcnt) break;
    }

    // ---- overflow accumulate (never taken for this input) ----
    for (int base = beg + STORE_CAP; base < end; base += 16) {
        int idx = base + ln;
        int s = ZROW; uint pw = 0;
        if (idx < end) {
            int ss = esrc[idx];
            float e = a_s[ss] + ad;
            e = (e > 0.f) ? e : 0.2f * e;
            pw = (uint)f2b(expf(e - m) * rden) | ((uint)f2b(dinv[ss] * dd) << 16);
            s = ss;
        }
        int cb = end - base; if (cb > 16) cb = 16;
        for (int jj = 0; jj < cb; ++jj) {
            int sa = __shfl(s, jj, 16);
            uint pa = (uint)__shfl((int)pw, jj, 16);
            fmacc(ldx((uint)sa), pa);
        }
    }

    // ---- epilogue: 16 lanes cover all 128 cols, 16B stores ----
    u8v xd = *(const u8v*)(xb + (size_t)d * 128 + ln * 8);
    int cs = cnt - 1;
    float rc = 1.f / (float)(cs > 1 ? cs : 1);
    u8v og, oc, os;
    #pragma unroll
    for (int k = 0; k < 8; ++k) {
        og[k] = f2b(tg[k]);
        oc[k] = f2b(tc[k]);
        os[k] = f2b((ts[k] - b2f(xd[k])) * rc);
    }
    size_t row = (size_t)d * 128 + ln * 8;
    *(u8v*)(tgb + row) = og;
    *(u8v*)(tcb + row) = oc;
    *(u8v*)(tsb + row) = os;
}

// ---------- BN final: reduce per-block partials, fold gamma/beta ----------
__global__ void k_bn_final(const float* __restrict__ pS, const float* __restrict__ pQ,
                           const float* __restrict__ gamma, const float* __restrict__ beta,
                           float* __restrict__ scale, float* __restrict__ shift)
{
    int j = blockIdx.x * 64 + threadIdx.x;
    if (j >= C3) return;
    float s = 0.f, q = 0.f;
    for (int r = 0; r < NBLK; ++r) {
        s += pS[(size_t)r * C3 + j];
        q += pQ[(size_t)r * C3 + j];
    }
    const float rn = 1.f / (float)NN;
    float mu  = s * rn;
    float var = q * rn - mu * mu;
    float sc  = gamma[j] * rsqrtf(var + 1e-5f);
    scale[j] = sc;
    shift[j] = beta[j] - mu * sc;
}

// ---------- in-place BN+relu of hcat (8 elems/thread, 16B ld/st) ----------
__global__ __launch_bounds__(256) void k_bnrelu(
    ushort* __restrict__ hch,
    const float* __restrict__ scale, const float* __restrict__ shift)
{
    int p = blockIdx.x * blockDim.x + threadIdx.x;
    if (p >= NN * 48) return;
    int cidx = (p % 48) * 8;
    size_t o = (size_t)p * 8;
    uint4 w = *(uint4*)(hch + o);
    uint wr[4] = {w.x, w.y, w.z, w.w};
    uint out[4];
    #pragma unroll
    for (int i = 0; i < 4; ++i) {
        ushort u0 = (ushort)(wr[i] & 0xffffu), u1 = (ushort)(wr[i] >> 16);
        int cc = cidx + i * 2;
        float v0 = b2f(u0) * scale[cc]     + shift[cc];
        float v1 = b2f(u1) * scale[cc + 1] + shift[cc + 1];
        v0 = v0 > 0.f ? v0 : 0.f;
        v1 = v1 > 0.f ? v1 : 0.f;
        out[i] = (uint)f2b(v0) | ((uint)f2b(v1) << 16);
    }
    uint4 r; r.x = out[0]; r.y = out[1]; r.z = out[2]; r.w = out[3];
    *(uint4*)(hch + o) = r;
}

extern "C" void kernel_launch(void* const* d_in, const int* in_sizes, int n_in,
                              void* d_out, int out_size, void* d_ws, size_t ws_size,
                              hipStream_t stream) {
    const float* x        = (const float*)d_in[0];
    const int*   ei       = (const int*)d_in[1];
    const float* W_gat    = (const float*)d_in[2];
    const float* att_src  = (const float*)d_in[3];
    const float* att_dst  = (const float*)d_in[4];
    const float* b_gat    = (const float*)d_in[5];
    const float* W_gcn    = (const float*)d_in[6];
    const float* b_gcn    = (const float*)d_in[7];
    const float* W_sage_l = (const float*)d_in[8];
    const float* b_sage_l = (const float*)d_in[9];
    const float* W_sage_r = (const float*)d_in[10];
    const float* W1       = (const float*)d_in[11];
    const float* b1       = (const float*)d_in[12];
    const float* W2       = (const float*)d_in[13];
    const float* b2       = (const float*)d_in[14];
    const float* W3       = (const float*)d_in[15];
    const float* b3       = (const float*)d_in[16];
    const float* gamma    = (const float*)d_in[17];
    const float* beta     = (const float*)d_in[18];

    const int* e_src = ei;
    const int* e_dst = ei + EE;

    // ---- workspace layout (16B-aligned) ----
    char* base = (char*)d_ws;
    size_t o = 0;
    ushort* hch  = (ushort*)(base + o); o += (size_t)NN * C3 * 2;
    ushort* tgb  = (ushort*)(base + o); o += (size_t)NN * 128 * 2;    // a1 overlay
    ushort* tcb  = (ushort*)(base + o); o += (size_t)NN * 128 * 2;
    ushort* tsb  = (ushort*)(base + o); o += (size_t)NN * 128 * 2;    // a2 overlay
    ushort* xb   = (ushort*)(base + o); o += (size_t)(NN + 1) * 128 * 2;  // +ZROW
    ushort* esrc = (ushort*)(base + o); o += ((size_t)(EE + NN) * 2 + 15) & ~15ull;
    int*    offs = (int*)(base + o);    o += (size_t)(NN + 16) * 4;
    float*  as_  = (float*)(base + o);  o += (size_t)NN * 4;
    float*  ad_  = (float*)(base + o);  o += (size_t)NN * 4;
    float*  dinv = (float*)(base + o);  o += (size_t)NN * 4;
    // --- zero-init region: bcnt only ---
    int*    bcnt = (int*)(base + o);    o += 128 * 4;
    // --- end zero region ---
    float*  pS   = (float*)(base + o);  o += (size_t)NBLK * C3 * 4;   // written fully
    float*  pQ   = (float*)(base + o);  o += (size_t)NBLK * C3 * 4;
    float*  scale= (float*)(base + o);  o += C3 * 4;
    float*  shift= (float*)(base + o);  o += C3 * 4;
    float*  w_as = (float*)(base + o);  o += 128 * 4;
    float*  w_ad = (float*)(base + o);  o += 128 * 4;
    ushort* btg  = (ushort*)(base + o); o += 128 * 128 * 2;
    ushort* btc  = (ushort*)(base + o); o += 128 * 128 * 2;
    ushort* btsg = (ushort*)(base + o); o += 128 * 256 * 2;
    ushort* bt1  = (ushort*)(base + o); o += 256 * 384 * 2;
    ushort* bt2  = (ushort*)(base + o); o += 128 * 256 * 2;
    ushort* bt3  = (ushort*)(base + o); o += 48 * 128 * 2;
    // overlays (temporally disjoint)
    ushort* a1 = tgb;                        // NN*256 ushorts (tgb+tcb)
    ushort* a2 = tsb;                        // NN*128
    uint*   ebuf = (uint*)hch;               // 98*16384*4B = 6.4MB << 38.4MB; hch first
                                             // written by k_gemm_prod, after k_csr_build

    hipMemsetAsync(bcnt, 0, 128 * 4, stream);

    // ---- weight prep ----
    k_splitw_all<<<817, 256, 0, stream>>>(W_gat, W_gcn, W_sage_l, W_sage_r, W1, W2, W3,
        att_src, att_dst, w_as, w_ad, btg, btc, btsg, bt1, bt2, bt3);
    // split x + attention dots (+ ZROW zero row)
    k_split_x_att<<<SPLIT_BLKS, 256, 0, stream>>>(x, w_as, w_ad, xb, as_, ad_);

    // ---- CSR build: bucket sort -> merged deg+scan -> in-LDS scatter ----
    k_bucket<<<BK_BLKS, 1024, 0, stream>>>(e_src, e_dst, bcnt, ebuf);
    k_degscan<<<NBUCK, 1024, 0, stream>>>(bcnt, ebuf, offs, dinv);
    k_csr_build<<<NBUCK, 1024, 0, stream>>>(bcnt, ebuf, offs, esrc);

    // ---- gather (16-lane quads, 1 dst/quad, 16B row loads) ----
    k_gather<<<(NN + 15) / 16, 256, 0, stream>>>(
        esrc, offs, as_, ad_, dinv, xb, tgb, tcb, tsb);

    // ---- producers: one launch, privatized BN partials ----
    k_gemm_prod<<<dim3(NBLK, 1, 3), 256, 0, stream>>>(
        tgb, tcb, tsb, xb, btg, btc, btsg,
        b_gat, b_gcn, b_sage_l, pS, pQ, hch);

    // ---- BN fold (partials reduce) + standalone BN+relu pass ----
    k_bn_final<<<6, 64, 0, stream>>>(pS, pQ, gamma, beta, scale, shift);
    k_bnrelu<<<(NN * 48 + 255) / 256, 256, 0, stream>>>(hch, scale, shift);

    // ---- MLP ----
    k_gemm2<8, 3, 1><<<dim3(2, NBLK), 256, 0, stream>>>(
        hch, 384, bt1, NN, 0, b1, nullptr, 0, a1, 256, 256);
    k_gemm2<8, 2, 0><<<dim3(NBLK, 1), 256, 0, stream>>>(
        a1, 256, bt2, NN, 0, b2, nullptr, 0, a2, 128, 128);
    k_gemm2<3, 1, 0><<<dim3(NBLK, 1), 256, 0, stream>>>(
        a2, 128, bt3, NN, 2, b3, (float*)d_out, NOUT, nullptr, 0, NOUT);
}

// Round 5
// 313.698 us; speedup vs baseline: 1.0708x; 1.0407x over previous
//
#include <hip/hip_runtime.h>
#include <cstdint>
#include <cstddef>

#define NN   50000
#define FIN  128
#define HD   128
#define EE   800000
#define C3   384   // 3*H
#define NOUT 40

#define NBLK ((NN + 127) / 128)                     // 391 row-blocks

#define SPLIT_BLKS ((NN + 4) / 4)                   // 12501 (includes ZROW)

#define NBUCK ((NN + 511) / 512)                    // 98 coarse dst-buckets
#define BCAP  16384                                 // per-bucket ebuf capacity
#define BK_BLKS ((EE + 8191) / 8192)                // 98 bucketing blocks
#define SCAP  12288                                 // csr_build LDS staging

#define RCAP      136                               // per-dst record slots (LDS)
#define STORE_CAP 128                               // fast-path record cap
#define ZROW NN                                     // zeroed xb row for pad records

#define LDSW 132   // padded epilogue LDS row stride (ushorts)

typedef __attribute__((ext_vector_type(8))) short s8v;   // 8 x bf16 (4 VGPR)
typedef __attribute__((ext_vector_type(4))) float f4v;   // MFMA acc
typedef __attribute__((ext_vector_type(8))) ushort u8v;  // 8 x bf16 (16B)

typedef const __attribute__((address_space(1))) unsigned int* guintp;
typedef __attribute__((address_space(3))) unsigned int* luintp;

static __device__ __forceinline__ void async_copy16(const void* g, void* l) {
    __builtin_amdgcn_global_load_lds((guintp)g, (luintp)l, 16, 0, 0);
}

// ---------- bf16 helpers ----------
static __device__ __forceinline__ float b2f(ushort u) {
    return __uint_as_float((unsigned)u << 16);
}
static __device__ __forceinline__ ushort f2b(float v) {
    unsigned u = __float_as_uint(v);
    unsigned r = u + 0x7fffu + ((u >> 16) & 1u);
    return (ushort)(r >> 16);
}

// ---------- x -> bf16 + attention dots; node NN is the zeroed pad row ----------
__global__ __launch_bounds__(256) void k_split_x_att(
    const float* __restrict__ x,
    const float* __restrict__ w_as, const float* __restrict__ w_ad,
    ushort* __restrict__ xb,
    float* __restrict__ a_s, float* __restrict__ a_d)
{
    int node = blockIdx.x * 4 + (threadIdx.x >> 6);
    if (node > NN) return;
    int lane = threadIdx.x & 63;
    size_t o = (size_t)node * 128 + lane * 2;
    if (node == NN) {                    // ZROW: all-zero pad row
        ushort2 z; z.x = 0; z.y = 0;
        *(ushort2*)(xb + o) = z;
        return;
    }
    float2 v  = *(const float2*)(x + o);
    { ushort2 u; u.x = f2b(v.x); u.y = f2b(v.y); *(ushort2*)(xb + o) = u; }
    float2 w1 = *(const float2*)(w_as + lane * 2);
    float2 w2 = *(const float2*)(w_ad + lane * 2);
    float s1 = v.x * w1.x + v.y * w1.y;
    float s2 = v.x * w2.x + v.y * w2.y;
    #pragma unroll
    for (int off = 32; off; off >>= 1) {
        s1 += __shfl_down(s1, off);
        s2 += __shfl_down(s2, off);
    }
    if (lane == 0) { a_s[node] = s1; a_d[node] = s2; }
}

// ---------- weight transposes (single bf16 plane) + att fold ----------
__global__ void k_splitw_all(
    const float* __restrict__ Wg, const float* __restrict__ Wc,
    const float* __restrict__ Wl, const float* __restrict__ Wr,
    const float* __restrict__ W1, const float* __restrict__ W2,
    const float* __restrict__ W3,
    const float* __restrict__ asv, const float* __restrict__ adv,
    float* __restrict__ w_as, float* __restrict__ w_ad,
    ushort* __restrict__ btg, ushort* __restrict__ btc,
    ushort* __restrict__ btsg,
    ushort* __restrict__ bt1, ushort* __restrict__ bt2,
    ushort* __restrict__ bt3)
{
    int ry = blockIdx.x;
    int t = threadIdx.x;
    if (ry == 816) {
        if (t < 128) {
            float s1 = 0.f, s2 = 0.f;
            for (int j = 0; j < 128; ++j) {
                float w = Wg[t * 128 + j];
                s1 += w * asv[j];
                s2 += w * adv[j];
            }
            w_as[t] = s1; w_ad[t] = s2;
        }
        return;
    }
    const float* W = nullptr; ushort* dh; int K, Nw, n;
    bool sage = false;
    if (ry < 128)      { n = ry;       K = 128; Nw = 128; W = Wg; dh = btg; }
    else if (ry < 256) { n = ry - 128; K = 128; Nw = 128; W = Wc; dh = btc; }
    else if (ry < 384) { n = ry - 256; K = 256; Nw = 128; sage = true; dh = btsg; }
    else if (ry < 640) { n = ry - 384; K = 384; Nw = 256; W = W1; dh = bt1; }
    else if (ry < 768) { n = ry - 640; K = 256; Nw = 128; W = W2; dh = bt2; }
    else               { n = ry - 768; K = 128; Nw = 40;  W = W3; dh = bt3; }
    for (int k = t; k < K; k += 256) {
        float v;
        if (sage) v = (k < 128) ? Wl[(size_t)k * 128 + n] : Wr[(size_t)(k - 128) * 128 + n];
        else      v = (n < Nw) ? W[(size_t)k * Nw + n] : 0.f;
        dh[(size_t)n * K + k] = f2b(v);
    }
}

// ---------- MFMA GEMM: bf16 A and B, both LDS-staged ----------
// mode 0: relu(acc+bias) -> bf16 store; mode 2: acc+bias -> fp32, cols<colmax
// BN=1: A-staging applies BN (scale/shift) + relu on the fly (replaces the
// standalone 77MB bnrelu pass; identical f32-compute/bf16-round numerics).
template<int NT, int NCH, int AX, int BN>
__global__ __launch_bounds__(256, 4) void k_gemm2(
    const ushort* __restrict__ A, int K,
    const ushort* __restrict__ Bt,
    int M, int mode,
    const float* __restrict__ bias,
    float* __restrict__ Cf, int ldc,
    ushort* __restrict__ Ch, int ldch,
    int colmax,
    const float* __restrict__ bnscale, const float* __restrict__ bnshift)
{
    constexpr int COLS = NT * 16;
    constexpr int HOPU = 8 * COLS;       // B 16B-units per 64-k half (1 plane)
    constexpr int KTOT = NCH * 128;

    __shared__ __align__(16) ushort S[16384];   // 32 KB union
    ushort* Bs = S;
    ushort* As = S + 8192;

    const int lane = threadIdx.x & 63;
    const int wave = threadIdx.x >> 6;
    const int quad = lane >> 4;
    const int ln15 = lane & 15;
    const int brow = AX ? blockIdx.y : blockIdx.x;
    const int bcol = AX ? blockIdx.x : blockIdx.y;
    const int row0 = brow * 128 + wave * 32;
    const int col0 = bcol * COLS;
    const int Rbase = brow * 128;

    auto stageB = [&](int c, int h) {
        for (int u0 = wave * 64; u0 < HOPU; u0 += 256) {
            int u  = u0 + lane;
            int kq  = u / COLS;
            int col = u - kq * COLS;
            int kk  = c * 128 + h * 64 + kq * 8;
            const ushort* gp = Bt + (size_t)(col0 + col) * KTOT + kk;
            async_copy16(gp, (char*)Bs + (size_t)u0 * 16);
        }
    };
    auto stageA = [&](int c, int h) {
        #pragma unroll
        for (int i = 0; i < 4; ++i) {
            int u0 = (wave * 4 + i) * 64;
            int u  = u0 + lane;
            int row = u >> 3;
            int s   = u & 7;
            int sg  = s ^ (row & 7);
            int rr = Rbase + row; if (rr > M - 1) rr = M - 1;
            int kk = c * 128 + h * 64 + sg * 8;
            if constexpr (BN) {
                uint4 w4 = *(const uint4*)(A + (size_t)rr * K + kk);
                float4 sca = *(const float4*)(bnscale + kk);
                float4 scb = *(const float4*)(bnscale + kk + 4);
                float4 sha = *(const float4*)(bnshift + kk);
                float4 shb = *(const float4*)(bnshift + kk + 4);
                float sc8[8] = {sca.x,sca.y,sca.z,sca.w,scb.x,scb.y,scb.z,scb.w};
                float sh8[8] = {sha.x,sha.y,sha.z,sha.w,shb.x,shb.y,shb.z,shb.w};
                uint wr[4] = {w4.x, w4.y, w4.z, w4.w};
                uint outw[4];
                #pragma unroll
                for (int p = 0; p < 4; ++p) {
                    float v0 = b2f((ushort)(wr[p] & 0xffffu)) * sc8[p*2]   + sh8[p*2];
                    float v1 = b2f((ushort)(wr[p] >> 16))     * sc8[p*2+1] + sh8[p*2+1];
                    v0 = v0 > 0.f ? v0 : 0.f;
                    v1 = v1 > 0.f ? v1 : 0.f;
                    outw[p] = (uint)f2b(v0) | ((uint)f2b(v1) << 16);
                }
                uint4 ov; ov.x = outw[0]; ov.y = outw[1]; ov.z = outw[2]; ov.w = outw[3];
                *(uint4*)(As + (size_t)u * 8) = ov;
            } else {
                const ushort* gp = A + (size_t)rr * K + kk;
                async_copy16(gp, (char*)As + (size_t)u0 * 16);
            }
        }
    };
    auto afrag = [&](int jj, int mt) -> s8v {
        int r = wave * 32 + mt * 16 + ln15;
        int sg = jj * 4 + quad;
        int unit = r * 8 + (sg ^ (r & 7));
        return *(const s8v*)(As + (size_t)unit * 8);
    };

    f4v acc[2][NT] = {};

    auto compute = [&](int jj) {
        s8v a0 = afrag(jj, 0);
        s8v a1 = afrag(jj, 1);
        #pragma unroll
        for (int t = 0; t < NT; ++t) {
            int ub = (jj * 4 + quad) * COLS + t * 16 + ln15;
            s8v b = *(const s8v*)(Bs + (size_t)ub * 8);
            acc[0][t] = __builtin_amdgcn_mfma_f32_16x16x32_bf16(a0, b, acc[0][t], 0, 0, 0);
            acc[1][t] = __builtin_amdgcn_mfma_f32_16x16x32_bf16(a1, b, acc[1][t], 0, 0, 0);
        }
    };

    stageB(0, 0); stageA(0, 0);
    __syncthreads();

    #pragma unroll
    for (int ph = 0; ph < NCH; ++ph) {
        #pragma unroll
        for (int h = 0; h < 2; ++h) {
            compute(0); compute(1);
            if (!(ph == NCH - 1 && h == 1)) {
                __syncthreads();
                int nc = ph, nh = h + 1;
                if (nh == 2) { nh = 0; ++nc; }
                stageB(nc, nh); stageA(nc, nh);
                __syncthreads();
            }
        }
    }

    if (NT == 8 && mode == 0) {
        __syncthreads();                          // staging LDS free now
        ushort* Lp = S + wave * 2176;             // wave-private quarter
        #pragma unroll
        for (int mt = 0; mt < 2; ++mt) {
            #pragma unroll
            for (int t = 0; t < NT; ++t) {
                int cc = col0 + t * 16 + ln15;
                #pragma unroll
                for (int r = 0; r < 4; ++r) {
                    float v = acc[mt][t][r] + bias[cc];
                    v = v > 0.f ? v : 0.f;
                    Lp[(quad * 4 + r) * LDSW + t * 16 + ln15] = f2b(v);
                }
            }
            int cb = (lane & 31) * 4;
            #pragma unroll
            for (int it = 0; it < 8; ++it) {
                int row2 = it * 2 + (lane >> 5);
                int rr = row0 + mt * 16 + row2;
                uint2 v = *(uint2*)(Lp + row2 * LDSW + cb);
                if (rr < M)
                    *(uint2*)(Ch + (size_t)rr * ldch + col0 + cb) = v;
            }
        }
    } else {
        #pragma unroll
        for (int t = 0; t < NT; ++t) {
            int cc = col0 + t * 16 + ln15;
            #pragma unroll
            for (int mt = 0; mt < 2; ++mt) {
                #pragma unroll
                for (int r = 0; r < 4; ++r) {
                    int rr = row0 + mt * 16 + quad * 4 + r;
                    if (rr < M && cc < colmax)
                        Cf[(size_t)rr * ldc + cc] = acc[mt][t][r] + bias[cc];
                }
            }
        }
    }
}

// ---------- merged producer GEMMs: z=0 GAT, z=1 GCN, z=2 SAGE ----------
// launch_bounds(256,3): keeps z0+z1 L2-resident hand-off (R14 lesson).
__global__ __launch_bounds__(256, 3) void k_gemm_prod(
    const ushort* __restrict__ tgb, const ushort* __restrict__ tcb,
    const ushort* __restrict__ tsb, const ushort* __restrict__ xb,
    const ushort* __restrict__ btg, const ushort* __restrict__ btc,
    const ushort* __restrict__ btsg,
    const float* __restrict__ bg, const float* __restrict__ bc,
    const float* __restrict__ bsl,
    float* __restrict__ pS, float* __restrict__ pQ,   // [NBLK][C3] partials
    ushort* __restrict__ hch)
{
    constexpr int COLS = 128;
    constexpr int HOPU = 8 * COLS;               // 1024 units per half
    __shared__ __align__(16) ushort S[16384];    // 32 KB union
    ushort* Bs = S;
    ushort* As = S + 8192;
    float* red = (float*)(S + 14336);            // 256 floats (dead As region)

    const int z = blockIdx.z;
    const ushort* A1 = (z == 0) ? tgb : (z == 1) ? tcb : tsb;
    const ushort* Bt = (z == 0) ? btg : (z == 1) ? btc : btsg;
    const float*  bias = (z == 0) ? bg : (z == 1) ? bc : bsl;
    const int nch = (z == 2) ? 2 : 1;
    const int ktot = nch * 128;

    const int lane = threadIdx.x & 63;
    const int wave = threadIdx.x >> 6;
    const int quad = lane >> 4;
    const int ln15 = lane & 15;
    const int row0 = blockIdx.x * 128 + wave * 32;
    const int Rbase = blockIdx.x * 128;

    auto stageB = [&](int c, int h) {
        for (int u0 = wave * 64; u0 < HOPU; u0 += 256) {
            int u  = u0 + lane;
            int kq  = u / COLS;
            int col = u - kq * COLS;
            int kk  = c * 128 + h * 64 + kq * 8;
            const ushort* gp = Bt + (size_t)col * ktot + kk;
            async_copy16(gp, (char*)Bs + (size_t)u0 * 16);
        }
    };
    auto stageA = [&](int c, int h) {
        #pragma unroll
        for (int i = 0; i < 4; ++i) {
            int u0 = (wave * 4 + i) * 64;
            int u  = u0 + lane;
            int row = u >> 3;
            int s   = u & 7;
            int sg  = s ^ (row & 7);
            int rr = Rbase + row; if (rr > NN - 1) rr = NN - 1;
            int kk = c * 128 + h * 64 + sg * 8;
            const ushort* gp = (kk < 128) ? (A1 + (size_t)rr * 128 + kk)
                                          : (xb + (size_t)rr * 128 + (kk - 128));
            async_copy16(gp, (char*)As + (size_t)u0 * 16);
        }
    };
    auto afrag = [&](int jj, int mt) -> s8v {
        int r = wave * 32 + mt * 16 + ln15;
        int sg = jj * 4 + quad;
        int unit = r * 8 + (sg ^ (r & 7));
        return *(const s8v*)(As + (size_t)unit * 8);
    };

    f4v acc[2][8] = {};

    auto compute = [&](int jj) {
        s8v a0 = afrag(jj, 0);
        s8v a1 = afrag(jj, 1);
        #pragma unroll
        for (int t = 0; t < 8; ++t) {
            int ub = (jj * 4 + quad) * COLS + t * 16 + ln15;
            s8v b = *(const s8v*)(Bs + (size_t)ub * 8);
            acc[0][t] = __builtin_amdgcn_mfma_f32_16x16x32_bf16(a0, b, acc[0][t], 0, 0, 0);
            acc[1][t] = __builtin_amdgcn_mfma_f32_16x16x32_bf16(a1, b, acc[1][t], 0, 0, 0);
        }
    };

    stageB(0, 0); stageA(0, 0);
    __syncthreads();

    for (int ph = 0; ph < nch; ++ph) {
        for (int h = 0; h < 2; ++h) {
            compute(0); compute(1);
            if (!(ph == nch - 1 && h == 1)) {
                __syncthreads();
                int nc = ph, nh = h + 1;
                if (nh == 2) { nh = 0; ++nc; }
                stageB(nc, nh); stageA(nc, nh);
                __syncthreads();
            }
        }
    }

    // LDS-transpose epilogue + per-lane BN partials
    __syncthreads();
    if (threadIdx.x < 256) red[threadIdx.x] = 0.f;   // As dead; red disjoint from Lp
    ushort* Lp = S + wave * 2176;
    float sp[8] = {}, qp[8] = {};
    #pragma unroll
    for (int mt = 0; mt < 2; ++mt) {
        #pragma unroll
        for (int t = 0; t < 8; ++t) {
            #pragma unroll
            for (int r = 0; r < 4; ++r) {
                int rr = row0 + mt * 16 + quad * 4 + r;
                float v = acc[mt][t][r] + bias[t * 16 + ln15];
                Lp[(quad * 4 + r) * LDSW + t * 16 + ln15] = f2b(v);
                if (rr < NN) { sp[t] += v; qp[t] += v * v; }
            }
        }
        int cb = (lane & 31) * 4;
        #pragma unroll
        for (int it = 0; it < 8; ++it) {
            int row2 = it * 2 + (lane >> 5);
            int rr = row0 + mt * 16 + row2;
            uint2 v = *(uint2*)(Lp + row2 * LDSW + cb);
            if (rr < NN)
                *(uint2*)(hch + (size_t)rr * C3 + z * 128 + cb) = v;
        }
    }
    // cross-wave LDS reduce (no contended global atomics)
    __syncthreads();
    #pragma unroll
    for (int t = 0; t < 8; ++t) {
        float s = sp[t], q = qp[t];
        s += __shfl_xor(s, 16); s += __shfl_xor(s, 32);
        q += __shfl_xor(q, 16); q += __shfl_xor(q, 32);
        if (quad == 0) {
            atomicAdd(&red[t * 16 + ln15], s);          // LDS atomic
            atomicAdd(&red[128 + t * 16 + ln15], q);
        }
    }
    __syncthreads();
    if (threadIdx.x < 128) {
        size_t o = (size_t)blockIdx.x * C3 + z * 128 + threadIdx.x;
        pS[o] = red[threadIdx.x];
        pQ[o] = red[128 + threadIdx.x];
    }
}

// ---------- Pass A: coarse bucket sort of edges, block-grouped writes ----------
__global__ __launch_bounds__(1024) void k_bucket(
    const int* __restrict__ e_src, const int* __restrict__ e_dst,
    int* __restrict__ bcnt, uint* __restrict__ ebuf)
{
    __shared__ uint sval[8192];          // 32 KB staged packed edges
    __shared__ int scnt[NBUCK], sbase[NBUCK];
    int t = threadIdx.x;
    if (t < NBUCK) scnt[t] = 0;
    __syncthreads();
    int e0 = blockIdx.x * 8192;
    #pragma unroll
    for (int i = 0; i < 8; ++i) {
        int g = e0 + i * 1024 + t;
        uint val = 0xffffffffu;          // sentinel (bucket 127 >= NBUCK)
        if (g < EE) {
            int d = e_dst[g];
            int s = e_src[g];
            int b = d >> 9;
            val = ((uint)b << 25) | ((uint)(d & 511) << 16) | (uint)s;
            atomicAdd(&scnt[b], 1);
        }
        sval[i * 1024 + t] = val;
    }
    __syncthreads();
    if (t < NBUCK) {
        sbase[t] = atomicAdd(&bcnt[t], scnt[t]);   // reserve contiguous run
        scnt[t] = 0;                                // reuse as local cursor
    }
    __syncthreads();
    #pragma unroll
    for (int i = 0; i < 8; ++i) {
        uint val = sval[i * 1024 + t];
        if (val != 0xffffffffu) {
            int b = val >> 25;
            int lo = atomicAdd(&scnt[b], 1);
            ebuf[(size_t)b * BCAP + sbase[b] + lo] = val;
        }
    }
}

// ---------- merged degree histogram + 2-level exclusive scan ----------
__global__ __launch_bounds__(1024) void k_degscan(
    const int* __restrict__ bcnt, const uint* __restrict__ ebuf,
    int* __restrict__ offs, float* __restrict__ dinv)
{
    __shared__ int hist[512];
    __shared__ int sh[256];
    __shared__ int btop;
    int b = blockIdx.x, t = threadIdx.x;
    int d0 = b * 512;
    if (t < 512) hist[t] = 0;
    __syncthreads();
    int nb = bcnt[b];
    const uint* eb = ebuf + (size_t)b * BCAP;
    for (int i = t; i < nb; i += 1024)
        atomicAdd(&hist[(eb[i] >> 16) & 511], 1);
    __syncthreads();
    if (t < 64) {                        // top-level exclusive prefix for bucket b
        int acc = 0;
        for (int i = t; i < b; i += 64) {
            int nd = NN - i * 512; if (nd > 512) nd = 512;
            acc += bcnt[i] + nd;
        }
        #pragma unroll
        for (int off = 32; off; off >>= 1) acc += __shfl_down(acc, off);
        if (t == 0) btop = acc;
    }
    int v0 = 0, v1 = 0;
    if (t < 256) {
        int i0g = d0 + t * 2;
        v0 = (i0g < NN) ? hist[t * 2] + 1 : 0;
        v1 = (i0g + 1 < NN) ? hist[t * 2 + 1] + 1 : 0;
        sh[t] = v0 + v1;
    }
    __syncthreads();
    for (int off = 1; off < 256; off <<= 1) {
        int u = 0;
        if (t < 256 && t >= off) u = sh[t - off];
        __syncthreads();
        if (t < 256) sh[t] += u;
        __syncthreads();
    }
    if (t < 256) {
        int pair = v0 + v1;
        int excl = sh[t] - pair + btop;
        int i0g = d0 + t * 2;
        if (i0g < NN)     { offs[i0g] = excl;          dinv[i0g] = rsqrtf((float)v0); }
        if (i0g + 1 < NN) { offs[i0g + 1] = excl + v0; dinv[i0g + 1] = rsqrtf((float)v1); }
        if (b == NBUCK - 1 && t == 255) offs[NN] = excl + pair;
    }
}

// ---------- Pass B: in-LDS scatter per bucket, coalesced esrc writes ----------
__global__ __launch_bounds__(1024) void k_csr_build(
    const int* __restrict__ bcnt, const uint* __restrict__ ebuf,
    const int* __restrict__ offs, ushort* __restrict__ esrc)
{
    __shared__ ushort sout[SCAP];        // 24 KB staging
    __shared__ int cur[512];
    int b = blockIdx.x, t = threadIdx.x;
    int d0 = b * 512;
    int ndst = NN - d0; if (ndst > 512) ndst = 512;
    int obase = offs[d0];
    if (t < ndst) cur[t] = offs[d0 + t] - obase;
    __syncthreads();
    int nb = bcnt[b];
    const uint* eb = ebuf + (size_t)b * BCAP;
    for (int i = t; i < nb; i += 1024) {
        uint val = eb[i];
        int slot = atomicAdd(&cur[(val >> 16) & 511], 1);
        sout[slot] = (ushort)(val & 0xffffu);
    }
    if (t < ndst) {                      // self loops
        int slot = atomicAdd(&cur[t], 1);
        sout[slot] = (ushort)(d0 + t);
    }
    __syncthreads();
    int total = offs[d0 + ndst] - obase;
    for (int i = t; i < total; i += 1024)
        esrc[obase + i] = sout[i];       // contiguous full-line writes
}

// ---------- CSR gather: 16-lane quads, 4-deep two-bank pipeline ----------
// Phase A-C unchanged (records in LDS). Phase D: two banks of 4 slots keep 4
// row-loads in flight per wave (16 rows across quads) to probe whether the
// 2.77 TB/s plateau is a concurrency limit or the fabric random-access floor.
// Summation order per dst is unchanged (ascending edge index).
__global__ __launch_bounds__(256, 6) void k_gather(
    const ushort* __restrict__ esrc, const int* __restrict__ offs,
    const float* __restrict__ a_s, const float* __restrict__ a_d,
    const float* __restrict__ dinv,
    const ushort* __restrict__ xb,
    ushort* __restrict__ tgb, ushort* __restrict__ tcb,
    ushort* __restrict__ tsb)
{
    __shared__ uint2 recs[16][RCAP];     // 17.4 KB: per-quad edge records
    int t = threadIdx.x;
    int qid = t >> 4;
    int ln = t & 15;
    int d = blockIdx.x * 16 + qid;
    if (d >= NN) return;
    uint2* rec = recs[qid];
    int beg = offs[d], end = offs[d + 1];
    int cnt = end - beg;
    float ad = a_d[d], dd = dinv[d];
    int stored = cnt < STORE_CAP ? cnt : STORE_CAP;

    // ---- phase A: e + wc into records, track max ----
    float mloc = -3.0e38f;
    for (int b = 0; b < cnt; b += 16) {
        int j = b + ln;
        if (j < cnt) {
            int s = esrc[beg + j];
            float e = a_s[s] + ad;
            e = (e > 0.f) ? e : 0.2f * e;
            mloc = fmaxf(mloc, e);
            if (j < STORE_CAP) {
                uint2 r;
                r.x = __float_as_uint(e);
                r.y = (uint)s | ((uint)f2b(dinv[s] * dd) << 16);
                rec[j] = r;
            }
        }
    }
    float m = mloc;
    #pragma unroll
    for (int off = 1; off < 16; off <<= 1) m = fmaxf(m, __shfl_xor(m, off, 16));

    // ---- phase B: exp + denom ----
    float denl = 0.f;
    for (int j = ln; j < stored; j += 16) {
        float ex = expf(__uint_as_float(rec[j].x) - m);
        denl += ex;
        rec[j].x = __float_as_uint(ex);
    }
    for (int idx = beg + STORE_CAP + ln; idx < end; idx += 16) {   // overflow (rare)
        int s = esrc[idx];
        float e = a_s[s] + ad;
        e = (e > 0.f) ? e : 0.2f * e;
        denl += expf(e - m);
    }
    float den = denl;
    #pragma unroll
    for (int off = 1; off < 16; off <<= 1) den += __shfl_xor(den, off, 16);
    float rden = 1.f / den;

    // ---- phase C: finalize packed records {pw, srow}; 8 pads {0, ZROW} ----
    for (int j = ln; j < stored; j += 16) {
        uint2 r = rec[j];
        uint2 q;
        q.x = (uint)f2b(__uint_as_float(r.x) * rden) | (r.y & 0xffff0000u);
        q.y = r.y & 0xffffu;
        rec[j] = q;
    }
    if (ln < 8) { uint2 q; q.x = 0u; q.y = (uint)ZROW; rec[stored + ln] = q; }

    // ---- phase D: 4-deep two-bank accumulate (4 edges/slot-bank) ----
    float tg[8] = {}, tc[8] = {}, ts[8] = {};
    const ushort* xbs = xb + ln * 8;
    auto ldx = [&](uint srow) -> u8v {
        return *(const u8v*)(xbs + (size_t)srow * 128);
    };
    auto fmacc = [&](u8v x8, uint pw) {
        float wg = __uint_as_float(pw << 16);          // bf16 low  -> f32
        float wc = __uint_as_float(pw & 0xffff0000u);  // bf16 high -> f32
        #pragma unroll
        for (int k = 0; k < 8; ++k) {
            float xv = b2f(x8[k]);
            tg[k] += wg * xv;
            tc[k] += wc * xv;
            ts[k] += xv;                               // pads: x = 0 (ZROW)
        }
    };

    int P4 = (stored + 3) & ~3;          // multiple of 4, >= 4
    uint pa0, pa1, pa2, pa3, pb0, pb1, pb2, pb3;
    u8v xa0, xa1, xa2, xa3, ya0, ya1, ya2, ya3;
    {
        uint2 r0 = rec[0], r1 = rec[1], r2 = rec[2], r3 = rec[3];
        pa0 = r0.x; xa0 = ldx(r0.y);
        pa1 = r1.x; xa1 = ldx(r1.y);
        pa2 = r2.x; xa2 = ldx(r2.y);
        pa3 = r3.x; xa3 = ldx(r3.y);
    }
    int j = 0;
    for (;;) {
        { uint2 r0 = rec[j+4], r1 = rec[j+5], r2 = rec[j+6], r3 = rec[j+7];
          pb0 = r0.x; ya0 = ldx(r0.y);
          pb1 = r1.x; ya1 = ldx(r1.y);
          pb2 = r2.x; ya2 = ldx(r2.y);
          pb3 = r3.x; ya3 = ldx(r3.y); }
        fmacc(xa0, pa0); fmacc(xa1, pa1); fmacc(xa2, pa2); fmacc(xa3, pa3);
        j += 4; if (j >= P4) break;
        { uint2 r0 = rec[j+4], r1 = rec[j+5], r2 = rec[j+6], r3 = rec[j+7];
          pa0 = r0.x; xa0 = ldx(r0.y);
          pa1 = r1.x; xa1 = ldx(r1.y);
          pa2 = r2.x; xa2 = ldx(r2.y);
          pa3 = r3.x; xa3 = ldx(r3.y); }
        fmacc(ya0, pb0); fmacc(ya1, pb1); fmacc(ya2, pb2); fmacc(ya3, pb3);
        j += 4; if (j >= P4) break;
    }

    // ---- overflow accumulate (never taken for this input) ----
    for (int base = beg + STORE_CAP; base < end; base += 16) {
        int idx = base + ln;
        int s = ZROW; uint pw = 0;
        if (idx < end) {
            int ss = esrc[idx];
            float e = a_s[ss] + ad;
            e = (e > 0.f) ? e : 0.2f * e;
            pw = (uint)f2b(expf(e - m) * rden) | ((uint)f2b(dinv[ss] * dd) << 16);
            s = ss;
        }
        int cb = end - base; if (cb > 16) cb = 16;
        for (int jj = 0; jj < cb; ++jj) {
            int sa = __shfl(s, jj, 16);
            uint pa = (uint)__shfl((int)pw, jj, 16);
            fmacc(ldx((uint)sa), pa);
        }
    }

    // ---- epilogue: 16 lanes cover all 128 cols, 16B stores ----
    u8v xd = *(const u8v*)(xb + (size_t)d * 128 + ln * 8);
    int cs = cnt - 1;
    float rc = 1.f / (float)(cs > 1 ? cs : 1);
    u8v og, oc, os;
    #pragma unroll
    for (int k = 0; k < 8; ++k) {
        og[k] = f2b(tg[k]);
        oc[k] = f2b(tc[k]);
        os[k] = f2b((ts[k] - b2f(xd[k])) * rc);
    }
    size_t row = (size_t)d * 128 + ln * 8;
    *(u8v*)(tgb + row) = og;
    *(u8v*)(tcb + row) = oc;
    *(u8v*)(tsb + row) = os;
}

// ---------- BN final: reduce per-block partials, fold gamma/beta ----------
__global__ void k_bn_final(const float* __restrict__ pS, const float* __restrict__ pQ,
                           const float* __restrict__ gamma, const float* __restrict__ beta,
                           float* __restrict__ scale, float* __restrict__ shift)
{
    int j = blockIdx.x * 64 + threadIdx.x;
    if (j >= C3) return;
    float s = 0.f, q = 0.f;
    for (int r = 0; r < NBLK; ++r) {
        s += pS[(size_t)r * C3 + j];
        q += pQ[(size_t)r * C3 + j];
    }
    const float rn = 1.f / (float)NN;
    float mu  = s * rn;
    float var = q * rn - mu * mu;
    float sc  = gamma[j] * rsqrtf(var + 1e-5f);
    scale[j] = sc;
    shift[j] = beta[j] - mu * sc;
}

extern "C" void kernel_launch(void* const* d_in, const int* in_sizes, int n_in,
                              void* d_out, int out_size, void* d_ws, size_t ws_size,
                              hipStream_t stream) {
    const float* x        = (const float*)d_in[0];
    const int*   ei       = (const int*)d_in[1];
    const float* W_gat    = (const float*)d_in[2];
    const float* att_src  = (const float*)d_in[3];
    const float* att_dst  = (const float*)d_in[4];
    const float* b_gat    = (const float*)d_in[5];
    const float* W_gcn    = (const float*)d_in[6];
    const float* b_gcn    = (const float*)d_in[7];
    const float* W_sage_l = (const float*)d_in[8];
    const float* b_sage_l = (const float*)d_in[9];
    const float* W_sage_r = (const float*)d_in[10];
    const float* W1       = (const float*)d_in[11];
    const float* b1       = (const float*)d_in[12];
    const float* W2       = (const float*)d_in[13];
    const float* b2       = (const float*)d_in[14];
    const float* W3       = (const float*)d_in[15];
    const float* b3       = (const float*)d_in[16];
    const float* gamma    = (const float*)d_in[17];
    const float* beta     = (const float*)d_in[18];

    const int* e_src = ei;
    const int* e_dst = ei + EE;

    // ---- workspace layout (16B-aligned) ----
    char* base = (char*)d_ws;
    size_t o = 0;
    ushort* hch  = (ushort*)(base + o); o += (size_t)NN * C3 * 2;
    ushort* tgb  = (ushort*)(base + o); o += (size_t)NN * 128 * 2;    // a1 overlay
    ushort* tcb  = (ushort*)(base + o); o += (size_t)NN * 128 * 2;
    ushort* tsb  = (ushort*)(base + o); o += (size_t)NN * 128 * 2;    // a2 overlay
    ushort* xb   = (ushort*)(base + o); o += (size_t)(NN + 1) * 128 * 2;  // +ZROW
    ushort* esrc = (ushort*)(base + o); o += ((size_t)(EE + NN) * 2 + 15) & ~15ull;
    int*    offs = (int*)(base + o);    o += (size_t)(NN + 16) * 4;
    float*  as_  = (float*)(base + o);  o += (size_t)NN * 4;
    float*  ad_  = (float*)(base + o);  o += (size_t)NN * 4;
    float*  dinv = (float*)(base + o);  o += (size_t)NN * 4;
    // --- zero-init region: bcnt only ---
    int*    bcnt = (int*)(base + o);    o += 128 * 4;
    // --- end zero region ---
    float*  pS   = (float*)(base + o);  o += (size_t)NBLK * C3 * 4;   // written fully
    float*  pQ   = (float*)(base + o);  o += (size_t)NBLK * C3 * 4;
    float*  scale= (float*)(base + o);  o += C3 * 4;
    float*  shift= (float*)(base + o);  o += C3 * 4;
    float*  w_as = (float*)(base + o);  o += 128 * 4;
    float*  w_ad = (float*)(base + o);  o += 128 * 4;
    ushort* btg  = (ushort*)(base + o); o += 128 * 128 * 2;
    ushort* btc  = (ushort*)(base + o); o += 128 * 128 * 2;
    ushort* btsg = (ushort*)(base + o); o += 128 * 256 * 2;
    ushort* bt1  = (ushort*)(base + o); o += 256 * 384 * 2;
    ushort* bt2  = (ushort*)(base + o); o += 128 * 256 * 2;
    ushort* bt3  = (ushort*)(base + o); o += 48 * 128 * 2;
    // overlays (temporally disjoint)
    ushort* a1 = tgb;                        // NN*256 ushorts (tgb+tcb)
    ushort* a2 = tsb;                        // NN*128
    uint*   ebuf = (uint*)hch;               // 6.4MB; hch first written by k_gemm_prod

    hipMemsetAsync(bcnt, 0, 128 * 4, stream);

    // ---- weight prep ----
    k_splitw_all<<<817, 256, 0, stream>>>(W_gat, W_gcn, W_sage_l, W_sage_r, W1, W2, W3,
        att_src, att_dst, w_as, w_ad, btg, btc, btsg, bt1, bt2, bt3);
    // split x + attention dots (+ ZROW zero row)
    k_split_x_att<<<SPLIT_BLKS, 256, 0, stream>>>(x, w_as, w_ad, xb, as_, ad_);

    // ---- CSR build: bucket sort -> merged deg+scan -> in-LDS scatter ----
    k_bucket<<<BK_BLKS, 1024, 0, stream>>>(e_src, e_dst, bcnt, ebuf);
    k_degscan<<<NBUCK, 1024, 0, stream>>>(bcnt, ebuf, offs, dinv);
    k_csr_build<<<NBUCK, 1024, 0, stream>>>(bcnt, ebuf, offs, esrc);

    // ---- gather (16-lane quads, 4-deep two-bank pipeline) ----
    k_gather<<<(NN + 15) / 16, 256, 0, stream>>>(
        esrc, offs, as_, ad_, dinv, xb, tgb, tcb, tsb);

    // ---- producers: one launch, privatized BN partials ----
    k_gemm_prod<<<dim3(NBLK, 1, 3), 256, 0, stream>>>(
        tgb, tcb, tsb, xb, btg, btc, btsg,
        b_gat, b_gcn, b_sage_l, pS, pQ, hch);

    // ---- BN fold (partials reduce); BN+relu now fused into MLP-L1 staging ----
    k_bn_final<<<6, 64, 0, stream>>>(pS, pQ, gamma, beta, scale, shift);

    // ---- MLP ----
    k_gemm2<8, 3, 1, 1><<<dim3(2, NBLK), 256, 0, stream>>>(
        hch, 384, bt1, NN, 0, b1, nullptr, 0, a1, 256, 256, scale, shift);
    k_gemm2<8, 2, 0, 0><<<dim3(NBLK, 1), 256, 0, stream>>>(
        a1, 256, bt2, NN, 0, b2, nullptr, 0, a2, 128, 128, nullptr, nullptr);
    k_gemm2<3, 1, 0, 0><<<dim3(NBLK, 1), 256, 0, stream>>>(
        a2, 128, bt3, NN, 2, b3, (float*)d_out, NOUT, nullptr, 0, NOUT, nullptr, nullptr);
}

// Round 6
// 310.162 us; speedup vs baseline: 1.0831x; 1.0114x over previous
//
#include <hip/hip_runtime.h>
#include <cstdint>
#include <cstddef>

#define NN   50000
#define FIN  128
#define HD   128
#define EE   800000
#define C3   384   // 3*H
#define NOUT 40

#define NBLK ((NN + 127) / 128)                     // 391 row-blocks

#define SPLIT_BLKS ((NN + 4) / 4)                   // 12501 (includes ZROW)

#define NBUCK ((NN + 511) / 512)                    // 98 coarse dst-buckets
#define BCAP  16384                                 // per-bucket ebuf capacity
#define BK_BLKS ((EE + 8191) / 8192)                // 98 bucketing blocks
#define SCAP  12288                                 // csr_build LDS staging

#define RCAP      136                               // per-dst record slots (LDS)
#define STORE_CAP 128                               // fast-path record cap
#define ZROW NN                                     // zeroed xb row for pad records

#define LDSW 132   // padded epilogue LDS row stride (ushorts)

typedef __attribute__((ext_vector_type(8))) short s8v;   // 8 x bf16 (4 VGPR)
typedef __attribute__((ext_vector_type(4))) float f4v;   // MFMA acc
typedef __attribute__((ext_vector_type(8))) ushort u8v;  // 8 x bf16 (16B)

typedef const __attribute__((address_space(1))) unsigned int* guintp;
typedef __attribute__((address_space(3))) unsigned int* luintp;

static __device__ __forceinline__ void async_copy16(const void* g, void* l) {
    __builtin_amdgcn_global_load_lds((guintp)g, (luintp)l, 16, 0, 0);
}

// ---------- bf16 helpers ----------
static __device__ __forceinline__ float b2f(ushort u) {
    return __uint_as_float((unsigned)u << 16);
}
static __device__ __forceinline__ ushort f2b(float v) {
    unsigned u = __float_as_uint(v);
    unsigned r = u + 0x7fffu + ((u >> 16) & 1u);
    return (ushort)(r >> 16);
}

// ---------- x -> bf16 + attention dots; node NN is the zeroed pad row ----------
__global__ __launch_bounds__(256) void k_split_x_att(
    const float* __restrict__ x,
    const float* __restrict__ w_as, const float* __restrict__ w_ad,
    ushort* __restrict__ xb,
    float* __restrict__ a_s, float* __restrict__ a_d)
{
    int node = blockIdx.x * 4 + (threadIdx.x >> 6);
    if (node > NN) return;
    int lane = threadIdx.x & 63;
    size_t o = (size_t)node * 128 + lane * 2;
    if (node == NN) {                    // ZROW: all-zero pad row
        ushort2 z; z.x = 0; z.y = 0;
        *(ushort2*)(xb + o) = z;
        return;
    }
    float2 v  = *(const float2*)(x + o);
    { ushort2 u; u.x = f2b(v.x); u.y = f2b(v.y); *(ushort2*)(xb + o) = u; }
    float2 w1 = *(const float2*)(w_as + lane * 2);
    float2 w2 = *(const float2*)(w_ad + lane * 2);
    float s1 = v.x * w1.x + v.y * w1.y;
    float s2 = v.x * w2.x + v.y * w2.y;
    #pragma unroll
    for (int off = 32; off; off >>= 1) {
        s1 += __shfl_down(s1, off);
        s2 += __shfl_down(s2, off);
    }
    if (lane == 0) { a_s[node] = s1; a_d[node] = s2; }
}

// ---------- weight transposes (single bf16 plane) + att fold ----------
__global__ void k_splitw_all(
    const float* __restrict__ Wg, const float* __restrict__ Wc,
    const float* __restrict__ Wl, const float* __restrict__ Wr,
    const float* __restrict__ W1, const float* __restrict__ W2,
    const float* __restrict__ W3,
    const float* __restrict__ asv, const float* __restrict__ adv,
    float* __restrict__ w_as, float* __restrict__ w_ad,
    ushort* __restrict__ btg, ushort* __restrict__ btc,
    ushort* __restrict__ btsg,
    ushort* __restrict__ bt1, ushort* __restrict__ bt2,
    ushort* __restrict__ bt3)
{
    int ry = blockIdx.x;
    int t = threadIdx.x;
    if (ry == 816) {
        if (t < 128) {
            float s1 = 0.f, s2 = 0.f;
            for (int j = 0; j < 128; ++j) {
                float w = Wg[t * 128 + j];
                s1 += w * asv[j];
                s2 += w * adv[j];
            }
            w_as[t] = s1; w_ad[t] = s2;
        }
        return;
    }
    const float* W = nullptr; ushort* dh; int K, Nw, n;
    bool sage = false;
    if (ry < 128)      { n = ry;       K = 128; Nw = 128; W = Wg; dh = btg; }
    else if (ry < 256) { n = ry - 128; K = 128; Nw = 128; W = Wc; dh = btc; }
    else if (ry < 384) { n = ry - 256; K = 256; Nw = 128; sage = true; dh = btsg; }
    else if (ry < 640) { n = ry - 384; K = 384; Nw = 256; W = W1; dh = bt1; }
    else if (ry < 768) { n = ry - 640; K = 256; Nw = 128; W = W2; dh = bt2; }
    else               { n = ry - 768; K = 128; Nw = 40;  W = W3; dh = bt3; }
    for (int k = t; k < K; k += 256) {
        float v;
        if (sage) v = (k < 128) ? Wl[(size_t)k * 128 + n] : Wr[(size_t)(k - 128) * 128 + n];
        else      v = (n < Nw) ? W[(size_t)k * Nw + n] : 0.f;
        dh[(size_t)n * K + k] = f2b(v);
    }
}

// ---------- MFMA GEMM: bf16 A and B, both DMA-staged via LDS ----------
// mode 0: relu(acc+bias) -> bf16 store; mode 2: acc+bias -> fp32, cols<colmax
// BN=1: BN (scale/shift from LDS) + relu applied to A-fragments at afrag-read
// time (each As unit is read exactly once per tile, so total VALU equals the
// old standalone bnrelu pass; staging stays pure async DMA -> latency hidden).
template<int NT, int NCH, int AX, int BN>
__global__ __launch_bounds__(256, BN ? 4 : 5) void k_gemm2(
    const ushort* __restrict__ A, int K,
    const ushort* __restrict__ Bt,
    int M, int mode,
    const float* __restrict__ bias,
    float* __restrict__ Cf, int ldc,
    ushort* __restrict__ Ch, int ldch,
    int colmax,
    const float* __restrict__ bnscale, const float* __restrict__ bnshift)
{
    constexpr int COLS = NT * 16;
    constexpr int HOPU = 8 * COLS;       // B 16B-units per 64-k half (1 plane)
    constexpr int KTOT = NCH * 128;

    __shared__ __align__(16) ushort S[16384];   // 32 KB union
    __shared__ float bns[BN ? 768 : 4];         // BN scale[384] + shift[384]
    ushort* Bs = S;
    ushort* As = S + 8192;

    const int lane = threadIdx.x & 63;
    const int wave = threadIdx.x >> 6;
    const int quad = lane >> 4;
    const int ln15 = lane & 15;
    const int brow = AX ? blockIdx.y : blockIdx.x;
    const int bcol = AX ? blockIdx.x : blockIdx.y;
    const int row0 = brow * 128 + wave * 32;
    const int col0 = bcol * COLS;
    const int Rbase = brow * 128;

    auto stageB = [&](int c, int h) {
        for (int u0 = wave * 64; u0 < HOPU; u0 += 256) {
            int u  = u0 + lane;
            int kq  = u / COLS;
            int col = u - kq * COLS;
            int kk  = c * 128 + h * 64 + kq * 8;
            const ushort* gp = Bt + (size_t)(col0 + col) * KTOT + kk;
            async_copy16(gp, (char*)Bs + (size_t)u0 * 16);
        }
    };
    auto stageA = [&](int c, int h) {
        #pragma unroll
        for (int i = 0; i < 4; ++i) {
            int u0 = (wave * 4 + i) * 64;
            int u  = u0 + lane;
            int row = u >> 3;
            int s   = u & 7;
            int sg  = s ^ (row & 7);
            int rr = Rbase + row; if (rr > M - 1) rr = M - 1;
            int kk = c * 128 + h * 64 + sg * 8;
            const ushort* gp = A + (size_t)rr * K + kk;
            async_copy16(gp, (char*)As + (size_t)u0 * 16);
        }
    };
    auto afrag = [&](int jj, int mt) -> s8v {
        int r = wave * 32 + mt * 16 + ln15;
        int sg = jj * 4 + quad;
        int unit = r * 8 + (sg ^ (r & 7));
        return *(const s8v*)(As + (size_t)unit * 8);
    };

    f4v acc[2][NT] = {};

    auto compute = [&](int jj, int kk0) {
        s8v a0 = afrag(jj, 0);
        s8v a1 = afrag(jj, 1);
        if constexpr (BN) {
            int cb0 = kk0 + (jj * 4 + quad) * 8;
            #pragma unroll
            for (int e = 0; e < 8; ++e) {
                float sc = bns[cb0 + e];
                float sh = bns[384 + cb0 + e];
                float v0 = b2f((ushort)a0[e]) * sc + sh;
                float v1 = b2f((ushort)a1[e]) * sc + sh;
                v0 = v0 > 0.f ? v0 : 0.f;
                v1 = v1 > 0.f ? v1 : 0.f;
                a0[e] = (short)f2b(v0);
                a1[e] = (short)f2b(v1);
            }
        }
        #pragma unroll
        for (int t = 0; t < NT; ++t) {
            int ub = (jj * 4 + quad) * COLS + t * 16 + ln15;
            s8v b = *(const s8v*)(Bs + (size_t)ub * 8);
            acc[0][t] = __builtin_amdgcn_mfma_f32_16x16x32_bf16(a0, b, acc[0][t], 0, 0, 0);
            acc[1][t] = __builtin_amdgcn_mfma_f32_16x16x32_bf16(a1, b, acc[1][t], 0, 0, 0);
        }
    };

    if constexpr (BN) {
        for (int j = threadIdx.x; j < 384; j += 256) {
            bns[j] = bnscale[j];
            bns[384 + j] = bnshift[j];
        }
    }
    stageB(0, 0); stageA(0, 0);
    __syncthreads();

    #pragma unroll
    for (int ph = 0; ph < NCH; ++ph) {
        #pragma unroll
        for (int h = 0; h < 2; ++h) {
            int kk0 = ph * 128 + h * 64;
            compute(0, kk0); compute(1, kk0);
            if (!(ph == NCH - 1 && h == 1)) {
                __syncthreads();
                int nc = ph, nh = h + 1;
                if (nh == 2) { nh = 0; ++nc; }
                stageB(nc, nh); stageA(nc, nh);
                __syncthreads();
            }
        }
    }

    if (NT == 8 && mode == 0) {
        __syncthreads();                          // staging LDS free now
        ushort* Lp = S + wave * 2176;             // wave-private quarter
        #pragma unroll
        for (int mt = 0; mt < 2; ++mt) {
            #pragma unroll
            for (int t = 0; t < NT; ++t) {
                int cc = col0 + t * 16 + ln15;
                #pragma unroll
                for (int r = 0; r < 4; ++r) {
                    float v = acc[mt][t][r] + bias[cc];
                    v = v > 0.f ? v : 0.f;
                    Lp[(quad * 4 + r) * LDSW + t * 16 + ln15] = f2b(v);
                }
            }
            int cb = (lane & 31) * 4;
            #pragma unroll
            for (int it = 0; it < 8; ++it) {
                int row2 = it * 2 + (lane >> 5);
                int rr = row0 + mt * 16 + row2;
                uint2 v = *(uint2*)(Lp + row2 * LDSW + cb);
                if (rr < M)
                    *(uint2*)(Ch + (size_t)rr * ldch + col0 + cb) = v;
            }
        }
    } else {
        #pragma unroll
        for (int t = 0; t < NT; ++t) {
            int cc = col0 + t * 16 + ln15;
            #pragma unroll
            for (int mt = 0; mt < 2; ++mt) {
                #pragma unroll
                for (int r = 0; r < 4; ++r) {
                    int rr = row0 + mt * 16 + quad * 4 + r;
                    if (rr < M && cc < colmax)
                        Cf[(size_t)rr * ldc + cc] = acc[mt][t][r] + bias[cc];
                }
            }
        }
    }
}

// ---------- merged producer GEMMs: z=0 GAT, z=1 GCN, z=2 SAGE ----------
// launch_bounds(256,3): keeps z0+z1 L2-resident hand-off (R14 lesson).
__global__ __launch_bounds__(256, 3) void k_gemm_prod(
    const ushort* __restrict__ tgb, const ushort* __restrict__ tcb,
    const ushort* __restrict__ tsb, const ushort* __restrict__ xb,
    const ushort* __restrict__ btg, const ushort* __restrict__ btc,
    const ushort* __restrict__ btsg,
    const float* __restrict__ bg, const float* __restrict__ bc,
    const float* __restrict__ bsl,
    float* __restrict__ pS, float* __restrict__ pQ,   // [NBLK][C3] partials
    ushort* __restrict__ hch)
{
    constexpr int COLS = 128;
    constexpr int HOPU = 8 * COLS;               // 1024 units per half
    __shared__ __align__(16) ushort S[16384];    // 32 KB union
    ushort* Bs = S;
    ushort* As = S + 8192;
    float* red = (float*)(S + 14336);            // 256 floats (dead As region)

    const int z = blockIdx.z;
    const ushort* A1 = (z == 0) ? tgb : (z == 1) ? tcb : tsb;
    const ushort* Bt = (z == 0) ? btg : (z == 1) ? btc : btsg;
    const float*  bias = (z == 0) ? bg : (z == 1) ? bc : bsl;
    const int nch = (z == 2) ? 2 : 1;
    const int ktot = nch * 128;

    const int lane = threadIdx.x & 63;
    const int wave = threadIdx.x >> 6;
    const int quad = lane >> 4;
    const int ln15 = lane & 15;
    const int row0 = blockIdx.x * 128 + wave * 32;
    const int Rbase = blockIdx.x * 128;

    auto stageB = [&](int c, int h) {
        for (int u0 = wave * 64; u0 < HOPU; u0 += 256) {
            int u  = u0 + lane;
            int kq  = u / COLS;
            int col = u - kq * COLS;
            int kk  = c * 128 + h * 64 + kq * 8;
            const ushort* gp = Bt + (size_t)col * ktot + kk;
            async_copy16(gp, (char*)Bs + (size_t)u0 * 16);
        }
    };
    auto stageA = [&](int c, int h) {
        #pragma unroll
        for (int i = 0; i < 4; ++i) {
            int u0 = (wave * 4 + i) * 64;
            int u  = u0 + lane;
            int row = u >> 3;
            int s   = u & 7;
            int sg  = s ^ (row & 7);
            int rr = Rbase + row; if (rr > NN - 1) rr = NN - 1;
            int kk = c * 128 + h * 64 + sg * 8;
            const ushort* gp = (kk < 128) ? (A1 + (size_t)rr * 128 + kk)
                                          : (xb + (size_t)rr * 128 + (kk - 128));
            async_copy16(gp, (char*)As + (size_t)u0 * 16);
        }
    };
    auto afrag = [&](int jj, int mt) -> s8v {
        int r = wave * 32 + mt * 16 + ln15;
        int sg = jj * 4 + quad;
        int unit = r * 8 + (sg ^ (r & 7));
        return *(const s8v*)(As + (size_t)unit * 8);
    };

    f4v acc[2][8] = {};

    auto compute = [&](int jj) {
        s8v a0 = afrag(jj, 0);
        s8v a1 = afrag(jj, 1);
        #pragma unroll
        for (int t = 0; t < 8; ++t) {
            int ub = (jj * 4 + quad) * COLS + t * 16 + ln15;
            s8v b = *(const s8v*)(Bs + (size_t)ub * 8);
            acc[0][t] = __builtin_amdgcn_mfma_f32_16x16x32_bf16(a0, b, acc[0][t], 0, 0, 0);
            acc[1][t] = __builtin_amdgcn_mfma_f32_16x16x32_bf16(a1, b, acc[1][t], 0, 0, 0);
        }
    };

    stageB(0, 0); stageA(0, 0);
    __syncthreads();

    for (int ph = 0; ph < nch; ++ph) {
        for (int h = 0; h < 2; ++h) {
            compute(0); compute(1);
            if (!(ph == nch - 1 && h == 1)) {
                __syncthreads();
                int nc = ph, nh = h + 1;
                if (nh == 2) { nh = 0; ++nc; }
                stageB(nc, nh); stageA(nc, nh);
                __syncthreads();
            }
        }
    }

    // LDS-transpose epilogue + per-lane BN partials
    __syncthreads();
    if (threadIdx.x < 256) red[threadIdx.x] = 0.f;   // As dead; red disjoint from Lp
    ushort* Lp = S + wave * 2176;
    float sp[8] = {}, qp[8] = {};
    #pragma unroll
    for (int mt = 0; mt < 2; ++mt) {
        #pragma unroll
        for (int t = 0; t < 8; ++t) {
            #pragma unroll
            for (int r = 0; r < 4; ++r) {
                int rr = row0 + mt * 16 + quad * 4 + r;
                float v = acc[mt][t][r] + bias[t * 16 + ln15];
                Lp[(quad * 4 + r) * LDSW + t * 16 + ln15] = f2b(v);
                if (rr < NN) { sp[t] += v; qp[t] += v * v; }
            }
        }
        int cb = (lane & 31) * 4;
        #pragma unroll
        for (int it = 0; it < 8; ++it) {
            int row2 = it * 2 + (lane >> 5);
            int rr = row0 + mt * 16 + row2;
            uint2 v = *(uint2*)(Lp + row2 * LDSW + cb);
            if (rr < NN)
                *(uint2*)(hch + (size_t)rr * C3 + z * 128 + cb) = v;
        }
    }
    // cross-wave LDS reduce (no contended global atomics)
    __syncthreads();
    #pragma unroll
    for (int t = 0; t < 8; ++t) {
        float s = sp[t], q = qp[t];
        s += __shfl_xor(s, 16); s += __shfl_xor(s, 32);
        q += __shfl_xor(q, 16); q += __shfl_xor(q, 32);
        if (quad == 0) {
            atomicAdd(&red[t * 16 + ln15], s);          // LDS atomic
            atomicAdd(&red[128 + t * 16 + ln15], q);
        }
    }
    __syncthreads();
    if (threadIdx.x < 128) {
        size_t o = (size_t)blockIdx.x * C3 + z * 128 + threadIdx.x;
        pS[o] = red[threadIdx.x];
        pQ[o] = red[128 + threadIdx.x];
    }
}

// ---------- Pass A: coarse bucket sort of edges, block-grouped writes ----------
__global__ __launch_bounds__(1024) void k_bucket(
    const int* __restrict__ e_src, const int* __restrict__ e_dst,
    int* __restrict__ bcnt, uint* __restrict__ ebuf)
{
    __shared__ uint sval[8192];          // 32 KB staged packed edges
    __shared__ int scnt[NBUCK], sbase[NBUCK];
    int t = threadIdx.x;
    if (t < NBUCK) scnt[t] = 0;
    __syncthreads();
    int e0 = blockIdx.x * 8192;
    #pragma unroll
    for (int i = 0; i < 8; ++i) {
        int g = e0 + i * 1024 + t;
        uint val = 0xffffffffu;          // sentinel (bucket 127 >= NBUCK)
        if (g < EE) {
            int d = e_dst[g];
            int s = e_src[g];
            int b = d >> 9;
            val = ((uint)b << 25) | ((uint)(d & 511) << 16) | (uint)s;
            atomicAdd(&scnt[b], 1);
        }
        sval[i * 1024 + t] = val;
    }
    __syncthreads();
    if (t < NBUCK) {
        sbase[t] = atomicAdd(&bcnt[t], scnt[t]);   // reserve contiguous run
        scnt[t] = 0;                                // reuse as local cursor
    }
    __syncthreads();
    #pragma unroll
    for (int i = 0; i < 8; ++i) {
        uint val = sval[i * 1024 + t];
        if (val != 0xffffffffu) {
            int b = val >> 25;
            int lo = atomicAdd(&scnt[b], 1);
            ebuf[(size_t)b * BCAP + sbase[b] + lo] = val;
        }
    }
}

// ---------- merged degree histogram + 2-level exclusive scan ----------
__global__ __launch_bounds__(1024) void k_degscan(
    const int* __restrict__ bcnt, const uint* __restrict__ ebuf,
    int* __restrict__ offs, float* __restrict__ dinv)
{
    __shared__ int hist[512];
    __shared__ int sh[256];
    __shared__ int btop;
    int b = blockIdx.x, t = threadIdx.x;
    int d0 = b * 512;
    if (t < 512) hist[t] = 0;
    __syncthreads();
    int nb = bcnt[b];
    const uint* eb = ebuf + (size_t)b * BCAP;
    for (int i = t; i < nb; i += 1024)
        atomicAdd(&hist[(eb[i] >> 16) & 511], 1);
    __syncthreads();
    if (t < 64) {                        // top-level exclusive prefix for bucket b
        int acc = 0;
        for (int i = t; i < b; i += 64) {
            int nd = NN - i * 512; if (nd > 512) nd = 512;
            acc += bcnt[i] + nd;
        }
        #pragma unroll
        for (int off = 32; off; off >>= 1) acc += __shfl_down(acc, off);
        if (t == 0) btop = acc;
    }
    int v0 = 0, v1 = 0;
    if (t < 256) {
        int i0g = d0 + t * 2;
        v0 = (i0g < NN) ? hist[t * 2] + 1 : 0;
        v1 = (i0g + 1 < NN) ? hist[t * 2 + 1] + 1 : 0;
        sh[t] = v0 + v1;
    }
    __syncthreads();
    for (int off = 1; off < 256; off <<= 1) {
        int u = 0;
        if (t < 256 && t >= off) u = sh[t - off];
        __syncthreads();
        if (t < 256) sh[t] += u;
        __syncthreads();
    }
    if (t < 256) {
        int pair = v0 + v1;
        int excl = sh[t] - pair + btop;
        int i0g = d0 + t * 2;
        if (i0g < NN)     { offs[i0g] = excl;          dinv[i0g] = rsqrtf((float)v0); }
        if (i0g + 1 < NN) { offs[i0g + 1] = excl + v0; dinv[i0g + 1] = rsqrtf((float)v1); }
        if (b == NBUCK - 1 && t == 255) offs[NN] = excl + pair;
    }
}

// ---------- Pass B: in-LDS scatter per bucket, coalesced esrc writes ----------
__global__ __launch_bounds__(1024) void k_csr_build(
    const int* __restrict__ bcnt, const uint* __restrict__ ebuf,
    const int* __restrict__ offs, ushort* __restrict__ esrc)
{
    __shared__ ushort sout[SCAP];        // 24 KB staging
    __shared__ int cur[512];
    int b = blockIdx.x, t = threadIdx.x;
    int d0 = b * 512;
    int ndst = NN - d0; if (ndst > 512) ndst = 512;
    int obase = offs[d0];
    if (t < ndst) cur[t] = offs[d0 + t] - obase;
    __syncthreads();
    int nb = bcnt[b];
    const uint* eb = ebuf + (size_t)b * BCAP;
    for (int i = t; i < nb; i += 1024) {
        uint val = eb[i];
        int slot = atomicAdd(&cur[(val >> 16) & 511], 1);
        sout[slot] = (ushort)(val & 0xffffu);
    }
    if (t < ndst) {                      // self loops
        int slot = atomicAdd(&cur[t], 1);
        sout[slot] = (ushort)(d0 + t);
    }
    __syncthreads();
    int total = offs[d0 + ndst] - obase;
    for (int i = t; i < total; i += 1024)
        esrc[obase + i] = sout[i];       // contiguous full-line writes
}

// ---------- CSR gather: 16-lane quads, 4-deep two-bank pipeline ----------
__global__ __launch_bounds__(256, 6) void k_gather(
    const ushort* __restrict__ esrc, const int* __restrict__ offs,
    const float* __restrict__ a_s, const float* __restrict__ a_d,
    const float* __restrict__ dinv,
    const ushort* __restrict__ xb,
    ushort* __restrict__ tgb, ushort* __restrict__ tcb,
    ushort* __restrict__ tsb)
{
    __shared__ uint2 recs[16][RCAP];     // 17.4 KB: per-quad edge records
    int t = threadIdx.x;
    int qid = t >> 4;
    int ln = t & 15;
    int d = blockIdx.x * 16 + qid;
    if (d >= NN) return;
    uint2* rec = recs[qid];
    int beg = offs[d], end = offs[d + 1];
    int cnt = end - beg;
    float ad = a_d[d], dd = dinv[d];
    int stored = cnt < STORE_CAP ? cnt : STORE_CAP;

    // ---- phase A: e + wc into records, track max ----
    float mloc = -3.0e38f;
    for (int b = 0; b < cnt; b += 16) {
        int j = b + ln;
        if (j < cnt) {
            int s = esrc[beg + j];
            float e = a_s[s] + ad;
            e = (e > 0.f) ? e : 0.2f * e;
            mloc = fmaxf(mloc, e);
            if (j < STORE_CAP) {
                uint2 r;
                r.x = __float_as_uint(e);
                r.y = (uint)s | ((uint)f2b(dinv[s] * dd) << 16);
                rec[j] = r;
            }
        }
    }
    float m = mloc;
    #pragma unroll
    for (int off = 1; off < 16; off <<= 1) m = fmaxf(m, __shfl_xor(m, off, 16));

    // ---- phase B: exp + denom ----
    float denl = 0.f;
    for (int j = ln; j < stored; j += 16) {
        float ex = expf(__uint_as_float(rec[j].x) - m);
        denl += ex;
        rec[j].x = __float_as_uint(ex);
    }
    for (int idx = beg + STORE_CAP + ln; idx < end; idx += 16) {   // overflow (rare)
        int s = esrc[idx];
        float e = a_s[s] + ad;
        e = (e > 0.f) ? e : 0.2f * e;
        denl += expf(e - m);
    }
    float den = denl;
    #pragma unroll
    for (int off = 1; off < 16; off <<= 1) den += __shfl_xor(den, off, 16);
    float rden = 1.f / den;

    // ---- phase C: finalize packed records {pw, srow}; 8 pads {0, ZROW} ----
    for (int j = ln; j < stored; j += 16) {
        uint2 r = rec[j];
        uint2 q;
        q.x = (uint)f2b(__uint_as_float(r.x) * rden) | (r.y & 0xffff0000u);
        q.y = r.y & 0xffffu;
        rec[j] = q;
    }
    if (ln < 8) { uint2 q; q.x = 0u; q.y = (uint)ZROW; rec[stored + ln] = q; }

    // ---- phase D: 4-deep two-bank accumulate (4 edges/slot-bank) ----
    float tg[8] = {}, tc[8] = {}, ts[8] = {};
    const ushort* xbs = xb + ln * 8;
    auto ldx = [&](uint srow) -> u8v {
        return *(const u8v*)(xbs + (size_t)srow * 128);
    };
    auto fmacc = [&](u8v x8, uint pw) {
        float wg = __uint_as_float(pw << 16);          // bf16 low  -> f32
        float wc = __uint_as_float(pw & 0xffff0000u);  // bf16 high -> f32
        #pragma unroll
        for (int k = 0; k < 8; ++k) {
            float xv = b2f(x8[k]);
            tg[k] += wg * xv;
            tc[k] += wc * xv;
            ts[k] += xv;                               // pads: x = 0 (ZROW)
        }
    };

    int P4 = (stored + 3) & ~3;          // multiple of 4, >= 4
    uint pa0, pa1, pa2, pa3, pb0, pb1, pb2, pb3;
    u8v xa0, xa1, xa2, xa3, ya0, ya1, ya2, ya3;
    {
        uint2 r0 = rec[0], r1 = rec[1], r2 = rec[2], r3 = rec[3];
        pa0 = r0.x; xa0 = ldx(r0.y);
        pa1 = r1.x; xa1 = ldx(r1.y);
        pa2 = r2.x; xa2 = ldx(r2.y);
        pa3 = r3.x; xa3 = ldx(r3.y);
    }
    int j = 0;
    for (;;) {
        { uint2 r0 = rec[j+4], r1 = rec[j+5], r2 = rec[j+6], r3 = rec[j+7];
          pb0 = r0.x; ya0 = ldx(r0.y);
          pb1 = r1.x; ya1 = ldx(r1.y);
          pb2 = r2.x; ya2 = ldx(r2.y);
          pb3 = r3.x; ya3 = ldx(r3.y); }
        fmacc(xa0, pa0); fmacc(xa1, pa1); fmacc(xa2, pa2); fmacc(xa3, pa3);
        j += 4; if (j >= P4) break;
        { uint2 r0 = rec[j+4], r1 = rec[j+5], r2 = rec[j+6], r3 = rec[j+7];
          pa0 = r0.x; xa0 = ldx(r0.y);
          pa1 = r1.x; xa1 = ldx(r1.y);
          pa2 = r2.x; xa2 = ldx(r2.y);
          pa3 = r3.x; xa3 = ldx(r3.y); }
        fmacc(ya0, pb0); fmacc(ya1, pb1); fmacc(ya2, pb2); fmacc(ya3, pb3);
        j += 4; if (j >= P4) break;
    }

    // ---- overflow accumulate (never taken for this input) ----
    for (int base = beg + STORE_CAP; base < end; base += 16) {
        int idx = base + ln;
        int s = ZROW; uint pw = 0;
        if (idx < end) {
            int ss = esrc[idx];
            float e = a_s[ss] + ad;
            e = (e > 0.f) ? e : 0.2f * e;
            pw = (uint)f2b(expf(e - m) * rden) | ((uint)f2b(dinv[ss] * dd) << 16);
            s = ss;
        }
        int cb = end - base; if (cb > 16) cb = 16;
        for (int jj = 0; jj < cb; ++jj) {
            int sa = __shfl(s, jj, 16);
            uint pa = (uint)__shfl((int)pw, jj, 16);
            fmacc(ldx((uint)sa), pa);
        }
    }

    // ---- epilogue: 16 lanes cover all 128 cols, 16B stores ----
    u8v xd = *(const u8v*)(xb + (size_t)d * 128 + ln * 8);
    int cs = cnt - 1;
    float rc = 1.f / (float)(cs > 1 ? cs : 1);
    u8v og, oc, os;
    #pragma unroll
    for (int k = 0; k < 8; ++k) {
        og[k] = f2b(tg[k]);
        oc[k] = f2b(tc[k]);
        os[k] = f2b((ts[k] - b2f(xd[k])) * rc);
    }
    size_t row = (size_t)d * 128 + ln * 8;
    *(u8v*)(tgb + row) = og;
    *(u8v*)(tcb + row) = oc;
    *(u8v*)(tsb + row) = os;
}

// ---------- BN final: reduce per-block partials, fold gamma/beta ----------
__global__ void k_bn_final(const float* __restrict__ pS, const float* __restrict__ pQ,
                           const float* __restrict__ gamma, const float* __restrict__ beta,
                           float* __restrict__ scale, float* __restrict__ shift)
{
    int j = blockIdx.x * 64 + threadIdx.x;
    if (j >= C3) return;
    float s = 0.f, q = 0.f;
    for (int r = 0; r < NBLK; ++r) {
        s += pS[(size_t)r * C3 + j];
        q += pQ[(size_t)r * C3 + j];
    }
    const float rn = 1.f / (float)NN;
    float mu  = s * rn;
    float var = q * rn - mu * mu;
    float sc  = gamma[j] * rsqrtf(var + 1e-5f);
    scale[j] = sc;
    shift[j] = beta[j] - mu * sc;
}

extern "C" void kernel_launch(void* const* d_in, const int* in_sizes, int n_in,
                              void* d_out, int out_size, void* d_ws, size_t ws_size,
                              hipStream_t stream) {
    const float* x        = (const float*)d_in[0];
    const int*   ei       = (const int*)d_in[1];
    const float* W_gat    = (const float*)d_in[2];
    const float* att_src  = (const float*)d_in[3];
    const float* att_dst  = (const float*)d_in[4];
    const float* b_gat    = (const float*)d_in[5];
    const float* W_gcn    = (const float*)d_in[6];
    const float* b_gcn    = (const float*)d_in[7];
    const float* W_sage_l = (const float*)d_in[8];
    const float* b_sage_l = (const float*)d_in[9];
    const float* W_sage_r = (const float*)d_in[10];
    const float* W1       = (const float*)d_in[11];
    const float* b1       = (const float*)d_in[12];
    const float* W2       = (const float*)d_in[13];
    const float* b2       = (const float*)d_in[14];
    const float* W3       = (const float*)d_in[15];
    const float* b3       = (const float*)d_in[16];
    const float* gamma    = (const float*)d_in[17];
    const float* beta     = (const float*)d_in[18];

    const int* e_src = ei;
    const int* e_dst = ei + EE;

    // ---- workspace layout (16B-aligned) ----
    char* base = (char*)d_ws;
    size_t o = 0;
    ushort* hch  = (ushort*)(base + o); o += (size_t)NN * C3 * 2;
    ushort* tgb  = (ushort*)(base + o); o += (size_t)NN * 128 * 2;    // a1 overlay
    ushort* tcb  = (ushort*)(base + o); o += (size_t)NN * 128 * 2;
    ushort* tsb  = (ushort*)(base + o); o += (size_t)NN * 128 * 2;    // a2 overlay
    ushort* xb   = (ushort*)(base + o); o += (size_t)(NN + 1) * 128 * 2;  // +ZROW
    ushort* esrc = (ushort*)(base + o); o += ((size_t)(EE + NN) * 2 + 15) & ~15ull;
    int*    offs = (int*)(base + o);    o += (size_t)(NN + 16) * 4;
    float*  as_  = (float*)(base + o);  o += (size_t)NN * 4;
    float*  ad_  = (float*)(base + o);  o += (size_t)NN * 4;
    float*  dinv = (float*)(base + o);  o += (size_t)NN * 4;
    // --- zero-init region: bcnt only ---
    int*    bcnt = (int*)(base + o);    o += 128 * 4;
    // --- end zero region ---
    float*  pS   = (float*)(base + o);  o += (size_t)NBLK * C3 * 4;   // written fully
    float*  pQ   = (float*)(base + o);  o += (size_t)NBLK * C3 * 4;
    float*  scale= (float*)(base + o);  o += C3 * 4;
    float*  shift= (float*)(base + o);  o += C3 * 4;
    float*  w_as = (float*)(base + o);  o += 128 * 4;
    float*  w_ad = (float*)(base + o);  o += 128 * 4;
    ushort* btg  = (ushort*)(base + o); o += 128 * 128 * 2;
    ushort* btc  = (ushort*)(base + o); o += 128 * 128 * 2;
    ushort* btsg = (ushort*)(base + o); o += 128 * 256 * 2;
    ushort* bt1  = (ushort*)(base + o); o += 256 * 384 * 2;
    ushort* bt2  = (ushort*)(base + o); o += 128 * 256 * 2;
    ushort* bt3  = (ushort*)(base + o); o += 48 * 128 * 2;
    // overlays (temporally disjoint)
    ushort* a1 = tgb;                        // NN*256 ushorts (tgb+tcb)
    ushort* a2 = tsb;                        // NN*128
    uint*   ebuf = (uint*)hch;               // 6.4MB; hch first written by k_gemm_prod

    hipMemsetAsync(bcnt, 0, 128 * 4, stream);

    // ---- weight prep ----
    k_splitw_all<<<817, 256, 0, stream>>>(W_gat, W_gcn, W_sage_l, W_sage_r, W1, W2, W3,
        att_src, att_dst, w_as, w_ad, btg, btc, btsg, bt1, bt2, bt3);
    // split x + attention dots (+ ZROW zero row)
    k_split_x_att<<<SPLIT_BLKS, 256, 0, stream>>>(x, w_as, w_ad, xb, as_, ad_);

    // ---- CSR build: bucket sort -> merged deg+scan -> in-LDS scatter ----
    k_bucket<<<BK_BLKS, 1024, 0, stream>>>(e_src, e_dst, bcnt, ebuf);
    k_degscan<<<NBUCK, 1024, 0, stream>>>(bcnt, ebuf, offs, dinv);
    k_csr_build<<<NBUCK, 1024, 0, stream>>>(bcnt, ebuf, offs, esrc);

    // ---- gather (16-lane quads, 4-deep two-bank pipeline) ----
    k_gather<<<(NN + 15) / 16, 256, 0, stream>>>(
        esrc, offs, as_, ad_, dinv, xb, tgb, tcb, tsb);

    // ---- producers: one launch, privatized BN partials ----
    k_gemm_prod<<<dim3(NBLK, 1, 3), 256, 0, stream>>>(
        tgb, tcb, tsb, xb, btg, btc, btsg,
        b_gat, b_gcn, b_sage_l, pS, pQ, hch);

    // ---- BN fold (partials reduce); BN+relu applied at L1 afrag-read ----
    k_bn_final<<<6, 64, 0, stream>>>(pS, pQ, gamma, beta, scale, shift);

    // ---- MLP ----
    k_gemm2<8, 3, 1, 1><<<dim3(2, NBLK), 256, 0, stream>>>(
        hch, 384, bt1, NN, 0, b1, nullptr, 0, a1, 256, 256, scale, shift);
    k_gemm2<8, 2, 0, 0><<<dim3(NBLK, 1), 256, 0, stream>>>(
        a1, 256, bt2, NN, 0, b2, nullptr, 0, a2, 128, 128, nullptr, nullptr);
    k_gemm2<3, 1, 0, 0><<<dim3(NBLK, 1), 256, 0, stream>>>(
        a2, 128, bt3, NN, 2, b3, (float*)d_out, NOUT, nullptr, 0, NOUT, nullptr, nullptr);
}

// Round 7
// 272.041 us; speedup vs baseline: 1.2348x; 1.1401x over previous
//
#include <hip/hip_runtime.h>
#include <cstdint>
#include <cstddef>

#define NN   50000
#define FIN  128
#define HD   128
#define EE   800000
#define C3   384   // 3*H
#define NOUT 40

#define NBLK ((NN + 127) / 128)                     // 391 row-blocks

#define NBUCK ((NN + 511) / 512)                    // 98 coarse dst-buckets
#define BCAP  16384                                 // per-bucket ebuf capacity
#define BK_BLKS ((EE + 8191) / 8192)                // 98 bucketing blocks
#define SCAP  12288                                 // csr staging (max ~9.2k)
#define SXB   ((NN + 16) / 16)                      // 3126 split_x blocks (16 nodes, incl ZROW)

#define RCAP      132                               // per-dst record slots (LDS)
#define STORE_CAP 128                               // fast-path record cap
#define ZROW NN                                     // zeroed xb row for pad records

#define LDSW 132   // padded epilogue LDS row stride (ushorts)
#define A2W  136   // gemm23 a2 LDS row stride (16B-aligned rows, 2-way banks)

typedef __attribute__((ext_vector_type(8))) short s8v;   // 8 x bf16 (4 VGPR)
typedef __attribute__((ext_vector_type(4))) float f4v;   // MFMA acc
typedef __attribute__((ext_vector_type(8))) ushort u8v;  // 8 x bf16 (16B)

typedef const __attribute__((address_space(1))) unsigned int* guintp;
typedef __attribute__((address_space(3))) unsigned int* luintp;

static __device__ __forceinline__ void async_copy16(const void* g, void* l) {
    __builtin_amdgcn_global_load_lds((guintp)g, (luintp)l, 16, 0, 0);
}

// ---------- bf16 helpers ----------
static __device__ __forceinline__ float b2f(ushort u) {
    return __uint_as_float((unsigned)u << 16);
}
static __device__ __forceinline__ ushort f2b(float v) {
    unsigned u = __float_as_uint(v);
    unsigned r = u + 0x7fffu + ((u >> 16) & 1u);
    return (ushort)(r >> 16);
}

// ---------- merged: edge bucket sort + weight transposes + att fold ----------
// blocks [0,98): bucket sort; blocks [98,915): weight prep (independent work).
__global__ __launch_bounds__(1024) void k_bucketw(
    const int* __restrict__ e_src, const int* __restrict__ e_dst,
    int* __restrict__ bcnt, uint* __restrict__ ebuf,
    const float* __restrict__ Wg, const float* __restrict__ Wc,
    const float* __restrict__ Wl, const float* __restrict__ Wr,
    const float* __restrict__ W1, const float* __restrict__ W2,
    const float* __restrict__ W3,
    const float* __restrict__ asv, const float* __restrict__ adv,
    float* __restrict__ w_as, float* __restrict__ w_ad,
    ushort* __restrict__ btg, ushort* __restrict__ btc,
    ushort* __restrict__ btsg,
    ushort* __restrict__ bt1, ushort* __restrict__ bt2,
    ushort* __restrict__ bt3)
{
    int t = threadIdx.x;
    if (blockIdx.x >= BK_BLKS) {
        int ry = blockIdx.x - BK_BLKS;
        if (ry == 816) {
            if (t < 128) {
                float s1 = 0.f, s2 = 0.f;
                for (int j = 0; j < 128; ++j) {
                    float w = Wg[t * 128 + j];
                    s1 += w * asv[j];
                    s2 += w * adv[j];
                }
                w_as[t] = s1; w_ad[t] = s2;
            }
            return;
        }
        const float* W = nullptr; ushort* dh; int K, Nw, n;
        bool sage = false;
        if (ry < 128)      { n = ry;       K = 128; Nw = 128; W = Wg; dh = btg; }
        else if (ry < 256) { n = ry - 128; K = 128; Nw = 128; W = Wc; dh = btc; }
        else if (ry < 384) { n = ry - 256; K = 256; Nw = 128; sage = true; dh = btsg; }
        else if (ry < 640) { n = ry - 384; K = 384; Nw = 256; W = W1; dh = bt1; }
        else if (ry < 768) { n = ry - 640; K = 256; Nw = 128; W = W2; dh = bt2; }
        else               { n = ry - 768; K = 128; Nw = 40;  W = W3; dh = bt3; }
        for (int k = t; k < K; k += 1024) {
            float v;
            if (sage) v = (k < 128) ? Wl[(size_t)k * 128 + n] : Wr[(size_t)(k - 128) * 128 + n];
            else      v = (n < Nw) ? W[(size_t)k * Nw + n] : 0.f;
            dh[(size_t)n * K + k] = f2b(v);
        }
        return;
    }
    __shared__ uint sval[8192];          // 32 KB staged packed edges
    __shared__ int scnt[NBUCK], sbase[NBUCK];
    if (t < NBUCK) scnt[t] = 0;
    __syncthreads();
    int e0 = blockIdx.x * 8192;
    #pragma unroll
    for (int i = 0; i < 8; ++i) {
        int g = e0 + i * 1024 + t;
        uint val = 0xffffffffu;          // sentinel (bucket 127 >= NBUCK)
        if (g < EE) {
            int d = e_dst[g];
            int s = e_src[g];
            int b = d >> 9;
            val = ((uint)b << 25) | ((uint)(d & 511) << 16) | (uint)s;
            atomicAdd(&scnt[b], 1);
        }
        sval[i * 1024 + t] = val;
    }
    __syncthreads();
    if (t < NBUCK) {
        sbase[t] = atomicAdd(&bcnt[t], scnt[t]);   // reserve contiguous run
        scnt[t] = 0;                                // reuse as local cursor
    }
    __syncthreads();
    #pragma unroll
    for (int i = 0; i < 8; ++i) {
        uint val = sval[i * 1024 + t];
        if (val != 0xffffffffu) {
            int b = val >> 25;
            int lo = atomicAdd(&scnt[b], 1);
            ebuf[(size_t)b * BCAP + sbase[b] + lo] = val;
        }
    }
}

// ---------- merged: (deg-hist + scan + in-LDS CSR scatter) AND x-split ----------
// blocks [0,98): per-bucket degree hist -> offs/dinv -> LDS scatter -> esrc.
// blocks [98,98+3126): x->bf16 + attention dots (16 nodes/block, incl ZROW).
__global__ __launch_bounds__(1024) void k_csrx(
    const int* __restrict__ bcnt, const uint* __restrict__ ebuf,
    int* __restrict__ offs, float* __restrict__ dinv,
    ushort* __restrict__ esrc,
    const float* __restrict__ x,
    const float* __restrict__ w_as, const float* __restrict__ w_ad,
    ushort* __restrict__ xb, float* __restrict__ a_s, float* __restrict__ a_d)
{
    int t = threadIdx.x;
    if (blockIdx.x >= NBUCK) {
        int node = (blockIdx.x - NBUCK) * 16 + (t >> 6);
        if (node > NN) return;
        int lane = t & 63;
        size_t o = (size_t)node * 128 + lane * 2;
        if (node == NN) {                // ZROW: all-zero pad row
            ushort2 z; z.x = 0; z.y = 0;
            *(ushort2*)(xb + o) = z;
            return;
        }
        float2 v  = *(const float2*)(x + o);
        { ushort2 u; u.x = f2b(v.x); u.y = f2b(v.y); *(ushort2*)(xb + o) = u; }
        float2 w1 = *(const float2*)(w_as + lane * 2);
        float2 w2 = *(const float2*)(w_ad + lane * 2);
        float s1 = v.x * w1.x + v.y * w1.y;
        float s2 = v.x * w2.x + v.y * w2.y;
        #pragma unroll
        for (int off = 32; off; off >>= 1) {
            s1 += __shfl_down(s1, off);
            s2 += __shfl_down(s2, off);
        }
        if (lane == 0) { a_s[node] = s1; a_d[node] = s2; }
        return;
    }
    __shared__ ushort sout[SCAP];        // 24 KB staging
    __shared__ int hist[512];            // degree hist, reused as cursors
    __shared__ int sh[256];
    __shared__ int btop_s;
    int b = blockIdx.x;
    int d0 = b * 512;
    int ndst = NN - d0; if (ndst > 512) ndst = 512;
    if (t < 512) hist[t] = 0;
    __syncthreads();
    int nb = bcnt[b];
    const uint* eb = ebuf + (size_t)b * BCAP;
    for (int i = t; i < nb; i += 1024)
        atomicAdd(&hist[(eb[i] >> 16) & 511], 1);
    __syncthreads();
    if (t < 64) {                        // top-level exclusive prefix for bucket b
        int acc = 0;
        for (int i = t; i < b; i += 64) {
            int nd = NN - i * 512; if (nd > 512) nd = 512;
            acc += bcnt[i] + nd;
        }
        #pragma unroll
        for (int off = 32; off; off >>= 1) acc += __shfl_down(acc, off);
        if (t == 0) btop_s = acc;
    }
    int v0 = 0, v1 = 0;
    if (t < 256) {
        int i0g = d0 + t * 2;
        v0 = (i0g < NN) ? hist[t * 2] + 1 : 0;
        v1 = (i0g + 1 < NN) ? hist[t * 2 + 1] + 1 : 0;
        sh[t] = v0 + v1;
    }
    __syncthreads();
    for (int off = 1; off < 256; off <<= 1) {
        int u = 0;
        if (t < 256 && t >= off) u = sh[t - off];
        __syncthreads();
        if (t < 256) sh[t] += u;
        __syncthreads();
    }
    if (t < 256) {
        int pair = v0 + v1;
        int lex = sh[t] - pair;          // bucket-local exclusive
        int excl = lex + btop_s;
        int i0g = d0 + t * 2;
        if (i0g < NN) {
            offs[i0g] = excl; dinv[i0g] = rsqrtf((float)v0);
            hist[t * 2] = lex;           // cursor (hist value consumed above)
        }
        if (i0g + 1 < NN) {
            offs[i0g + 1] = excl + v0; dinv[i0g + 1] = rsqrtf((float)v1);
            hist[t * 2 + 1] = lex + v0;
        }
        if (b == NBUCK - 1 && t == 255) offs[NN] = excl + pair;
    }
    __syncthreads();
    for (int i = t; i < nb; i += 1024) {
        uint val = eb[i];
        int slot = atomicAdd(&hist[(val >> 16) & 511], 1);
        sout[slot] = (ushort)(val & 0xffffu);
    }
    if (t < ndst) {                      // self loops
        int slot = atomicAdd(&hist[t], 1);
        sout[slot] = (ushort)(d0 + t);
    }
    __syncthreads();
    int total = nb + ndst;
    int obase = btop_s;
    for (int i = t; i < total; i += 1024)
        esrc[obase + i] = sout[i];       // contiguous full-line writes
}

// ---------- CSR gather: 16-lane quads, 2-deep dual-body (R4 form, no spill) ----
__global__ __launch_bounds__(256) void k_gather(
    const ushort* __restrict__ esrc, const int* __restrict__ offs,
    const float* __restrict__ a_s, const float* __restrict__ a_d,
    const float* __restrict__ dinv,
    const ushort* __restrict__ xb,
    ushort* __restrict__ tgb, ushort* __restrict__ tcb,
    ushort* __restrict__ tsb)
{
    __shared__ uint2 recs[16][RCAP];     // 16.5 KB: per-quad edge records
    int t = threadIdx.x;
    int qid = t >> 4;
    int ln = t & 15;
    int d = blockIdx.x * 16 + qid;
    if (d >= NN) return;
    uint2* rec = recs[qid];
    int beg = offs[d], end = offs[d + 1];
    int cnt = end - beg;
    float ad = a_d[d], dd = dinv[d];
    int stored = cnt < STORE_CAP ? cnt : STORE_CAP;

    // ---- phase A: e + wc into records, track max ----
    float mloc = -3.0e38f;
    for (int b = 0; b < cnt; b += 16) {
        int j = b + ln;
        if (j < cnt) {
            int s = esrc[beg + j];
            float e = a_s[s] + ad;
            e = (e > 0.f) ? e : 0.2f * e;
            mloc = fmaxf(mloc, e);
            if (j < STORE_CAP) {
                uint2 r;
                r.x = __float_as_uint(e);
                r.y = (uint)s | ((uint)f2b(dinv[s] * dd) << 16);
                rec[j] = r;
            }
        }
    }
    float m = mloc;
    #pragma unroll
    for (int off = 1; off < 16; off <<= 1) m = fmaxf(m, __shfl_xor(m, off, 16));

    // ---- phase B: exp + denom ----
    float denl = 0.f;
    for (int j = ln; j < stored; j += 16) {
        float ex = expf(__uint_as_float(rec[j].x) - m);
        denl += ex;
        rec[j].x = __float_as_uint(ex);
    }
    for (int idx = beg + STORE_CAP + ln; idx < end; idx += 16) {   // overflow (rare)
        int s = esrc[idx];
        float e = a_s[s] + ad;
        e = (e > 0.f) ? e : 0.2f * e;
        denl += expf(e - m);
    }
    float den = denl;
    #pragma unroll
    for (int off = 1; off < 16; off <<= 1) den += __shfl_xor(den, off, 16);
    float rden = 1.f / den;

    // ---- phase C: finalize packed records {pw, srow}; 2 pads {0, ZROW} ----
    for (int j = ln; j < stored; j += 16) {
        uint2 r = rec[j];
        uint2 q;
        q.x = (uint)f2b(__uint_as_float(r.x) * rden) | (r.y & 0xffff0000u);
        q.y = r.y & 0xffffu;
        rec[j] = q;
    }
    if (ln < 2) { uint2 q; q.x = 0u; q.y = (uint)ZROW; rec[stored + ln] = q; }

    // ---- phase D: hot accumulate (1 edge/quad-pass, dual-body pipeline) ----
    float tg[8] = {}, tc[8] = {}, ts[8] = {};
    const ushort* xbs = xb + ln * 8;
    auto ldx = [&](uint srow) -> u8v {
        return *(const u8v*)(xbs + (size_t)srow * 128);
    };
    auto fmacc = [&](u8v x8, uint pw) {
        float wg = __uint_as_float(pw << 16);          // bf16 low  -> f32
        float wc = __uint_as_float(pw & 0xffff0000u);  // bf16 high -> f32
        #pragma unroll
        for (int k = 0; k < 8; ++k) {
            float xv = b2f(x8[k]);
            tg[k] += wg * xv;
            tc[k] += wc * xv;
            ts[k] += xv;                               // pads: x = 0 (ZROW)
        }
    };

    int Pcnt = (stored + 1) & ~1;        // even, >= 2 (self-loop => cnt >= 1)
    uint2 rA = rec[0]; u8v xA = ldx(rA.y);
    uint2 rB; u8v xB;
    int j = 0;
    for (;;) {
        rB = rec[j + 1]; xB = ldx(rB.y); // prefetch (pads: safe)
        fmacc(xA, rA.x);
        if (++j >= Pcnt) break;
        rA = rec[j + 1]; xA = ldx(rA.y);
        fmacc(xB, rB.x);
        if (++j >= Pcnt) break;
    }

    // ---- overflow accumulate (never taken for this input) ----
    for (int base = beg + STORE_CAP; base < end; base += 16) {
        int idx = base + ln;
        int s = ZROW; uint pw = 0;
        if (idx < end) {
            int ss = esrc[idx];
            float e = a_s[ss] + ad;
            e = (e > 0.f) ? e : 0.2f * e;
            pw = (uint)f2b(expf(e - m) * rden) | ((uint)f2b(dinv[ss] * dd) << 16);
            s = ss;
        }
        int cb = end - base; if (cb > 16) cb = 16;
        for (int jj = 0; jj < cb; ++jj) {
            int sa = __shfl(s, jj, 16);
            uint pa = (uint)__shfl((int)pw, jj, 16);
            fmacc(ldx((uint)sa), pa);
        }
    }

    // ---- epilogue: 16 lanes cover all 128 cols, 16B stores ----
    u8v xd = *(const u8v*)(xb + (size_t)d * 128 + ln * 8);
    int cs = cnt - 1;
    float rc = 1.f / (float)(cs > 1 ? cs : 1);
    u8v og, oc, os;
    #pragma unroll
    for (int k = 0; k < 8; ++k) {
        og[k] = f2b(tg[k]);
        oc[k] = f2b(tc[k]);
        os[k] = f2b((ts[k] - b2f(xd[k])) * rc);
    }
    size_t row = (size_t)d * 128 + ln * 8;
    *(u8v*)(tgb + row) = og;
    *(u8v*)(tcb + row) = oc;
    *(u8v*)(tsb + row) = os;
}

// ---------- merged producer GEMMs: z=0 GAT, z=1 GCN, z=2 SAGE ----------
__global__ __launch_bounds__(256, 3) void k_gemm_prod(
    const ushort* __restrict__ tgb, const ushort* __restrict__ tcb,
    const ushort* __restrict__ tsb, const ushort* __restrict__ xb,
    const ushort* __restrict__ btg, const ushort* __restrict__ btc,
    const ushort* __restrict__ btsg,
    const float* __restrict__ bg, const float* __restrict__ bc,
    const float* __restrict__ bsl,
    float* __restrict__ pS, float* __restrict__ pQ,   // [NBLK][C3] partials
    ushort* __restrict__ hch)
{
    constexpr int COLS = 128;
    constexpr int HOPU = 8 * COLS;               // 1024 units per half
    __shared__ __align__(16) ushort S[16384];    // 32 KB union
    ushort* Bs = S;
    ushort* As = S + 8192;
    float* red = (float*)(S + 14336);            // 256 floats (dead As region)

    const int z = blockIdx.z;
    const ushort* A1 = (z == 0) ? tgb : (z == 1) ? tcb : tsb;
    const ushort* Bt = (z == 0) ? btg : (z == 1) ? btc : btsg;
    const float*  bias = (z == 0) ? bg : (z == 1) ? bc : bsl;
    const int nch = (z == 2) ? 2 : 1;
    const int ktot = nch * 128;

    const int lane = threadIdx.x & 63;
    const int wave = threadIdx.x >> 6;
    const int quad = lane >> 4;
    const int ln15 = lane & 15;
    const int row0 = blockIdx.x * 128 + wave * 32;
    const int Rbase = blockIdx.x * 128;

    auto stageB = [&](int c, int h) {
        for (int u0 = wave * 64; u0 < HOPU; u0 += 256) {
            int u  = u0 + lane;
            int kq  = u / COLS;
            int col = u - kq * COLS;
            int kk  = c * 128 + h * 64 + kq * 8;
            const ushort* gp = Bt + (size_t)col * ktot + kk;
            async_copy16(gp, (char*)Bs + (size_t)u0 * 16);
        }
    };
    auto stageA = [&](int c, int h) {
        #pragma unroll
        for (int i = 0; i < 4; ++i) {
            int u0 = (wave * 4 + i) * 64;
            int u  = u0 + lane;
            int row = u >> 3;
            int s   = u & 7;
            int sg  = s ^ (row & 7);
            int rr = Rbase + row; if (rr > NN - 1) rr = NN - 1;
            int kk = c * 128 + h * 64 + sg * 8;
            const ushort* gp = (kk < 128) ? (A1 + (size_t)rr * 128 + kk)
                                          : (xb + (size_t)rr * 128 + (kk - 128));
            async_copy16(gp, (char*)As + (size_t)u0 * 16);
        }
    };
    auto afrag = [&](int jj, int mt) -> s8v {
        int r = wave * 32 + mt * 16 + ln15;
        int sg = jj * 4 + quad;
        int unit = r * 8 + (sg ^ (r & 7));
        return *(const s8v*)(As + (size_t)unit * 8);
    };

    f4v acc[2][8] = {};

    auto compute = [&](int jj) {
        s8v a0 = afrag(jj, 0);
        s8v a1 = afrag(jj, 1);
        #pragma unroll
        for (int t = 0; t < 8; ++t) {
            int ub = (jj * 4 + quad) * COLS + t * 16 + ln15;
            s8v b = *(const s8v*)(Bs + (size_t)ub * 8);
            acc[0][t] = __builtin_amdgcn_mfma_f32_16x16x32_bf16(a0, b, acc[0][t], 0, 0, 0);
            acc[1][t] = __builtin_amdgcn_mfma_f32_16x16x32_bf16(a1, b, acc[1][t], 0, 0, 0);
        }
    };

    stageB(0, 0); stageA(0, 0);
    __syncthreads();

    for (int ph = 0; ph < nch; ++ph) {
        for (int h = 0; h < 2; ++h) {
            compute(0); compute(1);
            if (!(ph == nch - 1 && h == 1)) {
                __syncthreads();
                int nc = ph, nh = h + 1;
                if (nh == 2) { nh = 0; ++nc; }
                stageB(nc, nh); stageA(nc, nh);
                __syncthreads();
            }
        }
    }

    // LDS-transpose epilogue + per-lane BN partials
    __syncthreads();
    if (threadIdx.x < 256) red[threadIdx.x] = 0.f;   // As dead; red disjoint from Lp
    ushort* Lp = S + wave * 2176;
    float sp[8] = {}, qp[8] = {};
    #pragma unroll
    for (int mt = 0; mt < 2; ++mt) {
        #pragma unroll
        for (int t = 0; t < 8; ++t) {
            #pragma unroll
            for (int r = 0; r < 4; ++r) {
                int rr = row0 + mt * 16 + quad * 4 + r;
                float v = acc[mt][t][r] + bias[t * 16 + ln15];
                Lp[(quad * 4 + r) * LDSW + t * 16 + ln15] = f2b(v);
                if (rr < NN) { sp[t] += v; qp[t] += v * v; }
            }
        }
        int cb = (lane & 31) * 4;
        #pragma unroll
        for (int it = 0; it < 8; ++it) {
            int row2 = it * 2 + (lane >> 5);
            int rr = row0 + mt * 16 + row2;
            uint2 v = *(uint2*)(Lp + row2 * LDSW + cb);
            if (rr < NN)
                *(uint2*)(hch + (size_t)rr * C3 + z * 128 + cb) = v;
        }
    }
    // cross-wave LDS reduce (no contended global atomics)
    __syncthreads();
    #pragma unroll
    for (int t = 0; t < 8; ++t) {
        float s = sp[t], q = qp[t];
        s += __shfl_xor(s, 16); s += __shfl_xor(s, 32);
        q += __shfl_xor(q, 16); q += __shfl_xor(q, 32);
        if (quad == 0) {
            atomicAdd(&red[t * 16 + ln15], s);          // LDS atomic
            atomicAdd(&red[128 + t * 16 + ln15], q);
        }
    }
    __syncthreads();
    if (threadIdx.x < 128) {
        size_t o = (size_t)blockIdx.x * C3 + z * 128 + threadIdx.x;
        pS[o] = red[threadIdx.x];
        pQ[o] = red[128 + threadIdx.x];
    }
}

// ---------- BN final: 4 threads/column over the 391-row partials ----------
__global__ void k_bn_final(const float* __restrict__ pS, const float* __restrict__ pQ,
                           const float* __restrict__ gamma, const float* __restrict__ beta,
                           float* __restrict__ scale, float* __restrict__ shift)
{
    int t = threadIdx.x;
    int j = blockIdx.x * 64 + (t >> 2);
    int part = t & 3;
    if (j >= C3) return;
    float s = 0.f, q = 0.f;
    for (int r = part; r < NBLK; r += 4) {
        s += pS[(size_t)r * C3 + j];
        q += pQ[(size_t)r * C3 + j];
    }
    s += __shfl_down(s, 2); s += __shfl_down(s, 1);
    q += __shfl_down(q, 2); q += __shfl_down(q, 1);
    if (part == 0) {
        const float rn = 1.f / (float)NN;
        float mu  = s * rn;
        float var = q * rn - mu * mu;
        float sc  = gamma[j] * rsqrtf(var + 1e-5f);
        scale[j] = sc;
        shift[j] = beta[j] - mu * sc;
    }
}

// ---------- MFMA GEMM (L1): BN+relu at afrag-read, async-DMA staging ----------
template<int NT, int NCH, int AX, int BN>
__global__ __launch_bounds__(256, BN ? 4 : 5) void k_gemm2(
    const ushort* __restrict__ A, int K,
    const ushort* __restrict__ Bt,
    int M, int mode,
    const float* __restrict__ bias,
    float* __restrict__ Cf, int ldc,
    ushort* __restrict__ Ch, int ldch,
    int colmax,
    const float* __restrict__ bnscale, const float* __restrict__ bnshift)
{
    constexpr int COLS = NT * 16;
    constexpr int HOPU = 8 * COLS;       // B 16B-units per 64-k half (1 plane)
    constexpr int KTOT = NCH * 128;

    __shared__ __align__(16) ushort S[16384];   // 32 KB union
    __shared__ float bns[BN ? 768 : 4];         // BN scale[384] + shift[384]
    ushort* Bs = S;
    ushort* As = S + 8192;

    const int lane = threadIdx.x & 63;
    const int wave = threadIdx.x >> 6;
    const int quad = lane >> 4;
    const int ln15 = lane & 15;
    const int brow = AX ? blockIdx.y : blockIdx.x;
    const int bcol = AX ? blockIdx.x : blockIdx.y;
    const int row0 = brow * 128 + wave * 32;
    const int col0 = bcol * COLS;
    const int Rbase = brow * 128;

    auto stageB = [&](int c, int h) {
        for (int u0 = wave * 64; u0 < HOPU; u0 += 256) {
            int u  = u0 + lane;
            int kq  = u / COLS;
            int col = u - kq * COLS;
            int kk  = c * 128 + h * 64 + kq * 8;
            const ushort* gp = Bt + (size_t)(col0 + col) * KTOT + kk;
            async_copy16(gp, (char*)Bs + (size_t)u0 * 16);
        }
    };
    auto stageA = [&](int c, int h) {
        #pragma unroll
        for (int i = 0; i < 4; ++i) {
            int u0 = (wave * 4 + i) * 64;
            int u  = u0 + lane;
            int row = u >> 3;
            int s   = u & 7;
            int sg  = s ^ (row & 7);
            int rr = Rbase + row; if (rr > M - 1) rr = M - 1;
            int kk = c * 128 + h * 64 + sg * 8;
            const ushort* gp = A + (size_t)rr * K + kk;
            async_copy16(gp, (char*)As + (size_t)u0 * 16);
        }
    };
    auto afrag = [&](int jj, int mt) -> s8v {
        int r = wave * 32 + mt * 16 + ln15;
        int sg = jj * 4 + quad;
        int unit = r * 8 + (sg ^ (r & 7));
        return *(const s8v*)(As + (size_t)unit * 8);
    };

    f4v acc[2][NT] = {};

    auto compute = [&](int jj, int kk0) {
        s8v a0 = afrag(jj, 0);
        s8v a1 = afrag(jj, 1);
        if constexpr (BN) {
            int cb0 = kk0 + (jj * 4 + quad) * 8;
            #pragma unroll
            for (int e = 0; e < 8; ++e) {
                float sc = bns[cb0 + e];
                float sh = bns[384 + cb0 + e];
                float v0 = b2f((ushort)a0[e]) * sc + sh;
                float v1 = b2f((ushort)a1[e]) * sc + sh;
                v0 = v0 > 0.f ? v0 : 0.f;
                v1 = v1 > 0.f ? v1 : 0.f;
                a0[e] = (short)f2b(v0);
                a1[e] = (short)f2b(v1);
            }
        }
        #pragma unroll
        for (int t = 0; t < NT; ++t) {
            int ub = (jj * 4 + quad) * COLS + t * 16 + ln15;
            s8v b = *(const s8v*)(Bs + (size_t)ub * 8);
            acc[0][t] = __builtin_amdgcn_mfma_f32_16x16x32_bf16(a0, b, acc[0][t], 0, 0, 0);
            acc[1][t] = __builtin_amdgcn_mfma_f32_16x16x32_bf16(a1, b, acc[1][t], 0, 0, 0);
        }
    };

    if constexpr (BN) {
        for (int j = threadIdx.x; j < 384; j += 256) {
            bns[j] = bnscale[j];
            bns[384 + j] = bnshift[j];
        }
    }
    stageB(0, 0); stageA(0, 0);
    __syncthreads();

    #pragma unroll
    for (int ph = 0; ph < NCH; ++ph) {
        #pragma unroll
        for (int h = 0; h < 2; ++h) {
            int kk0 = ph * 128 + h * 64;
            compute(0, kk0); compute(1, kk0);
            if (!(ph == NCH - 1 && h == 1)) {
                __syncthreads();
                int nc = ph, nh = h + 1;
                if (nh == 2) { nh = 0; ++nc; }
                stageB(nc, nh); stageA(nc, nh);
                __syncthreads();
            }
        }
    }

    if (NT == 8 && mode == 0) {
        __syncthreads();                          // staging LDS free now
        ushort* Lp = S + wave * 2176;             // wave-private quarter
        #pragma unroll
        for (int mt = 0; mt < 2; ++mt) {
            #pragma unroll
            for (int t = 0; t < NT; ++t) {
                int cc = col0 + t * 16 + ln15;
                #pragma unroll
                for (int r = 0; r < 4; ++r) {
                    float v = acc[mt][t][r] + bias[cc];
                    v = v > 0.f ? v : 0.f;
                    Lp[(quad * 4 + r) * LDSW + t * 16 + ln15] = f2b(v);
                }
            }
            int cb = (lane & 31) * 4;
            #pragma unroll
            for (int it = 0; it < 8; ++it) {
                int row2 = it * 2 + (lane >> 5);
                int rr = row0 + mt * 16 + row2;
                uint2 v = *(uint2*)(Lp + row2 * LDSW + cb);
                if (rr < M)
                    *(uint2*)(Ch + (size_t)rr * ldch + col0 + cb) = v;
            }
        }
    } else {
        #pragma unroll
        for (int t = 0; t < NT; ++t) {
            int cc = col0 + t * 16 + ln15;
            #pragma unroll
            for (int mt = 0; mt < 2; ++mt) {
                #pragma unroll
                for (int r = 0; r < 4; ++r) {
                    int rr = row0 + mt * 16 + quad * 4 + r;
                    if (rr < M && cc < colmax)
                        Cf[(size_t)rr * ldc + cc] = acc[mt][t][r] + bias[cc];
                }
            }
        }
    }
}

// ---------- fused MLP L2+L3: a2 stays in LDS, out fp32 ----------
// GEMM2: a1[128x256] @ bt2 -> relu+bias -> A2 LDS [128][136] bf16.
// bt3 DMA'd into dead staging LDS during the epilogue; GEMM3 K=128 from LDS.
// MFMA K-order identical to the old separate L3 kernel -> bit-identical out.
__global__ __launch_bounds__(256, 2) void k_gemm23(
    const ushort* __restrict__ A,
    const ushort* __restrict__ Bt2, const ushort* __restrict__ Bt3,
    const float* __restrict__ b2v, const float* __restrict__ b3v,
    float* __restrict__ out)
{
    constexpr int COLS = 128;
    constexpr int HOPU = 1024;
    constexpr int KTOT = 256;
    __shared__ __align__(16) ushort S[16384];       // 32 KB staging; bt3 after
    __shared__ __align__(16) ushort A2[128 * A2W];  // 34 KB a2 bf16
    ushort* Bs = S;
    ushort* As = S + 8192;

    const int lane = threadIdx.x & 63;
    const int wave = threadIdx.x >> 6;
    const int quad = lane >> 4;
    const int ln15 = lane & 15;
    const int Rbase = blockIdx.x * 128;
    const int row0 = Rbase + wave * 32;

    auto stageB = [&](int c, int h) {
        for (int u0 = wave * 64; u0 < HOPU; u0 += 256) {
            int u  = u0 + lane;
            int kq  = u / COLS;
            int col = u - kq * COLS;
            int kk  = c * 128 + h * 64 + kq * 8;
            async_copy16(Bt2 + (size_t)col * KTOT + kk, (char*)Bs + (size_t)u0 * 16);
        }
    };
    auto stageA = [&](int c, int h) {
        #pragma unroll
        for (int i = 0; i < 4; ++i) {
            int u0 = (wave * 4 + i) * 64;
            int u  = u0 + lane;
            int row = u >> 3;
            int s   = u & 7;
            int sg  = s ^ (row & 7);
            int rr = Rbase + row; if (rr > NN - 1) rr = NN - 1;
            int kk = c * 128 + h * 64 + sg * 8;
            async_copy16(A + (size_t)rr * KTOT + kk, (char*)As + (size_t)u0 * 16);
        }
    };
    auto afrag = [&](int jj, int mt) -> s8v {
        int r = wave * 32 + mt * 16 + ln15;
        int sg = jj * 4 + quad;
        int unit = r * 8 + (sg ^ (r & 7));
        return *(const s8v*)(As + (size_t)unit * 8);
    };

    f4v acc[2][8] = {};
    auto compute = [&](int jj) {
        s8v a0 = afrag(jj, 0);
        s8v a1 = afrag(jj, 1);
        #pragma unroll
        for (int t = 0; t < 8; ++t) {
            int ub = (jj * 4 + quad) * COLS + t * 16 + ln15;
            s8v b = *(const s8v*)(Bs + (size_t)ub * 8);
            acc[0][t] = __builtin_amdgcn_mfma_f32_16x16x32_bf16(a0, b, acc[0][t], 0, 0, 0);
            acc[1][t] = __builtin_amdgcn_mfma_f32_16x16x32_bf16(a1, b, acc[1][t], 0, 0, 0);
        }
    };

    stageB(0, 0); stageA(0, 0);
    __syncthreads();
    #pragma unroll
    for (int ph = 0; ph < 2; ++ph) {
        #pragma unroll
        for (int h = 0; h < 2; ++h) {
            compute(0); compute(1);
            if (!(ph == 1 && h == 1)) {
                __syncthreads();
                int nc = ph, nh = h + 1;
                if (nh == 2) { nh = 0; ++nc; }
                stageB(nc, nh); stageA(nc, nh);
                __syncthreads();
            }
        }
    }

    __syncthreads();                     // staging dead; A2 not yet read
    // stage bt3 (48 cols x 128 k, both halves) into S — overlaps epilogue VALU
    for (int u0 = wave * 64; u0 < 768; u0 += 256) {
        int u = u0 + lane;
        int h = u / 384;
        int rem = u - h * 384;
        int kq = rem / 48;
        int col = rem - kq * 48;
        int kk = h * 64 + kq * 8;
        async_copy16(Bt3 + (size_t)col * 128 + kk, (char*)S + (size_t)u0 * 16);
    }
    // a2 = relu(acc + b2) -> LDS
    #pragma unroll
    for (int mt = 0; mt < 2; ++mt) {
        #pragma unroll
        for (int t = 0; t < 8; ++t) {
            int cc = t * 16 + ln15;
            float bb = b2v[cc];
            #pragma unroll
            for (int r = 0; r < 4; ++r) {
                int rl = wave * 32 + mt * 16 + quad * 4 + r;
                float v = acc[mt][t][r] + bb;
                v = v > 0.f ? v : 0.f;
                A2[(size_t)rl * A2W + cc] = f2b(v);
            }
        }
    }
    __syncthreads();                     // a2 written AND bt3 landed (vmcnt drain)

    // GEMM3: 128x40 = A2[128x128] @ bt3
    f4v acc3[2][3] = {};
    #pragma unroll
    for (int h = 0; h < 2; ++h) {
        #pragma unroll
        for (int jj = 0; jj < 2; ++jj) {
            int sg = jj * 4 + quad;
            int ko = h * 64 + sg * 8;
            s8v a0 = *(const s8v*)(A2 + (size_t)(wave * 32 + ln15) * A2W + ko);
            s8v a1 = *(const s8v*)(A2 + (size_t)(wave * 32 + 16 + ln15) * A2W + ko);
            #pragma unroll
            for (int t = 0; t < 3; ++t) {
                int ub = h * 384 + sg * 48 + t * 16 + ln15;
                s8v b = *(const s8v*)(S + (size_t)ub * 8);
                acc3[0][t] = __builtin_amdgcn_mfma_f32_16x16x32_bf16(a0, b, acc3[0][t], 0, 0, 0);
                acc3[1][t] = __builtin_amdgcn_mfma_f32_16x16x32_bf16(a1, b, acc3[1][t], 0, 0, 0);
            }
        }
    }
    #pragma unroll
    for (int t = 0; t < 3; ++t) {
        int cc = t * 16 + ln15;
        #pragma unroll
        for (int mt = 0; mt < 2; ++mt) {
            #pragma unroll
            for (int r = 0; r < 4; ++r) {
                int rr = row0 + mt * 16 + quad * 4 + r;
                if (rr < NN && cc < NOUT)
                    out[(size_t)rr * NOUT + cc] = acc3[mt][t][r] + b3v[cc];
            }
        }
    }
}

extern "C" void kernel_launch(void* const* d_in, const int* in_sizes, int n_in,
                              void* d_out, int out_size, void* d_ws, size_t ws_size,
                              hipStream_t stream) {
    const float* x        = (const float*)d_in[0];
    const int*   ei       = (const int*)d_in[1];
    const float* W_gat    = (const float*)d_in[2];
    const float* att_src  = (const float*)d_in[3];
    const float* att_dst  = (const float*)d_in[4];
    const float* b_gat    = (const float*)d_in[5];
    const float* W_gcn    = (const float*)d_in[6];
    const float* b_gcn    = (const float*)d_in[7];
    const float* W_sage_l = (const float*)d_in[8];
    const float* b_sage_l = (const float*)d_in[9];
    const float* W_sage_r = (const float*)d_in[10];
    const float* W1       = (const float*)d_in[11];
    const float* b1       = (const float*)d_in[12];
    const float* W2       = (const float*)d_in[13];
    const float* b2       = (const float*)d_in[14];
    const float* W3       = (const float*)d_in[15];
    const float* b3       = (const float*)d_in[16];
    const float* gamma    = (const float*)d_in[17];
    const float* beta     = (const float*)d_in[18];

    const int* e_src = ei;
    const int* e_dst = ei + EE;

    // ---- workspace layout (16B-aligned) ----
    char* base = (char*)d_ws;
    size_t o = 0;
    ushort* hch  = (ushort*)(base + o); o += (size_t)NN * C3 * 2;
    ushort* tgb  = (ushort*)(base + o); o += (size_t)NN * 128 * 2;    // a1 overlay
    ushort* tcb  = (ushort*)(base + o); o += (size_t)NN * 128 * 2;
    ushort* tsb  = (ushort*)(base + o); o += (size_t)NN * 128 * 2;
    ushort* xb   = (ushort*)(base + o); o += (size_t)(NN + 1) * 128 * 2;  // +ZROW
    ushort* esrc = (ushort*)(base + o); o += ((size_t)(EE + NN) * 2 + 15) & ~15ull;
    int*    offs = (int*)(base + o);    o += (size_t)(NN + 16) * 4;
    float*  as_  = (float*)(base + o);  o += (size_t)NN * 4;
    float*  ad_  = (float*)(base + o);  o += (size_t)NN * 4;
    float*  dinv = (float*)(base + o);  o += (size_t)NN * 4;
    // --- zero-init region: bcnt only ---
    int*    bcnt = (int*)(base + o);    o += 128 * 4;
    // --- end zero region ---
    float*  pS   = (float*)(base + o);  o += (size_t)NBLK * C3 * 4;   // written fully
    float*  pQ   = (float*)(base + o);  o += (size_t)NBLK * C3 * 4;
    float*  scale= (float*)(base + o);  o += C3 * 4;
    float*  shift= (float*)(base + o);  o += C3 * 4;
    float*  w_as = (float*)(base + o);  o += 128 * 4;
    float*  w_ad = (float*)(base + o);  o += 128 * 4;
    ushort* btg  = (ushort*)(base + o); o += 128 * 128 * 2;
    ushort* btc  = (ushort*)(base + o); o += 128 * 128 * 2;
    ushort* btsg = (ushort*)(base + o); o += 128 * 256 * 2;
    ushort* bt1  = (ushort*)(base + o); o += 256 * 384 * 2;
    ushort* bt2  = (ushort*)(base + o); o += 128 * 256 * 2;
    ushort* bt3  = (ushort*)(base + o); o += 48 * 128 * 2;
    // overlays (temporally disjoint)
    ushort* a1 = tgb;                        // NN*256 ushorts (tgb+tcb)
    uint*   ebuf = (uint*)hch;               // 6.4MB; hch first written by k_gemm_prod

    hipMemsetAsync(bcnt, 0, 128 * 4, stream);

    // 1. bucket sort + weight prep (merged)
    k_bucketw<<<BK_BLKS + 817, 1024, 0, stream>>>(
        e_src, e_dst, bcnt, ebuf,
        W_gat, W_gcn, W_sage_l, W_sage_r, W1, W2, W3,
        att_src, att_dst, w_as, w_ad, btg, btc, btsg, bt1, bt2, bt3);

    // 2. CSR build (deg+scan+scatter) + x split (merged)
    k_csrx<<<NBUCK + SXB, 1024, 0, stream>>>(
        bcnt, ebuf, offs, dinv, esrc,
        x, w_as, w_ad, xb, as_, ad_);

    // 3. gather (16-lane quads, 2-deep pipeline, no spill)
    k_gather<<<(NN + 15) / 16, 256, 0, stream>>>(
        esrc, offs, as_, ad_, dinv, xb, tgb, tcb, tsb);

    // 4. producers: one launch, privatized BN partials
    k_gemm_prod<<<dim3(NBLK, 1, 3), 256, 0, stream>>>(
        tgb, tcb, tsb, xb, btg, btc, btsg,
        b_gat, b_gcn, b_sage_l, pS, pQ, hch);

    // 5. BN fold (4 threads/col partials reduce)
    k_bn_final<<<6, 256, 0, stream>>>(pS, pQ, gamma, beta, scale, shift);

    // 6. MLP L1 (BN+relu at afrag)
    k_gemm2<8, 3, 1, 1><<<dim3(2, NBLK), 256, 0, stream>>>(
        hch, 384, bt1, NN, 0, b1, nullptr, 0, a1, 256, 256, scale, shift);

    // 7. MLP L2+L3 fused (a2 in LDS, fp32 out)
    k_gemm23<<<NBLK, 256, 0, stream>>>(a1, bt2, bt3, b2, b3, (float*)d_out);
}